// Round 10
// baseline (389.794 us; speedup 1.0000x reference)
//
#include <hip/hip_runtime.h>
#include <stdint.h>

#define N_ 8192
#define M_ 4096
#define FIN_ 256
#define F_ 128
#define B_ 2048

typedef __attribute__((ext_vector_type(8))) short vs8;
typedef __attribute__((ext_vector_type(8))) __bf16 vb8;
typedef __attribute__((ext_vector_type(4))) float vf4;

union ABu { vs8 s; vb8 b; };

__device__ __forceinline__ vf4 mfma16(const ABu& a, const ABu& b, vf4 c) {
    return __builtin_amdgcn_mfma_f32_16x16x32_bf16(a.b, b.b, c, 0, 0, 0);
}
__device__ __forceinline__ unsigned short f2b(float x) {
    union { float f; unsigned u; } v; v.f = x;
    unsigned r = v.u + 0x7fffu + ((v.u >> 16) & 1u);
    return (unsigned short)(r >> 16);
}
__device__ __forceinline__ float lrelu(float x) { return x > 0.f ? x : 0.2f * x; }

// ---- prep: W[256][128] f32 -> WT[128][256] bf16  +  zero u_in/v_in/stats ----
__global__ void k_prep(const float* __restrict__ W1, const float* __restrict__ W2,
                       unsigned short* __restrict__ W1T, unsigned short* __restrict__ W2T,
                       float4* __restrict__ Z, int nz4) {
    int id = blockIdx.x * 256 + threadIdx.x;
    if (id < 65536) {
        const float* W = (id < 32768) ? W1 : W2;
        unsigned short* WT = (id < 32768) ? W1T : W2T;
        int o = id & 32767;
        int f = o >> 8, k = o & 255;
        WT[o] = f2b(W[k * F_ + f]);
    } else {
        int z = id - 65536;
        if (z < nz4) Z[z] = make_float4(0.f, 0.f, 0.f, 0.f);
    }
}

// ---- FUSED: h = X@W (MFMA); write h2 f32, packed hP[kblk][f][32] bf16, s1/s2 row-dots ----
__global__ __launch_bounds__(256) void k_hgemmF(const float* __restrict__ Rin, const float* __restrict__ Sin,
                                                const unsigned short* __restrict__ W1T,
                                                const unsigned short* __restrict__ W2T,
                                                const float* __restrict__ a,
                                                float* __restrict__ h2,
                                                unsigned short* __restrict__ h1P, unsigned short* __restrict__ h2P,
                                                float* __restrict__ s1, float* __restrict__ s2) {
    __shared__ unsigned short tb[16][136];               // 16 rows x 128 f, padded
    __shared__ float sred[4][16];
    int t = threadIdx.x;
    int w = t >> 6, l = t & 63, lr = l & 15, lg = l >> 4;
    int gr = blockIdx.x * 16;
    const float* X; const unsigned short* WT; unsigned short* HP; float* sout; const float* av;
    int row0; bool isH2;
    if (gr < M_) { X = Rin; WT = W1T; HP = h1P; sout = s1; av = a;      row0 = gr;      isH2 = false; }
    else         { X = Sin; WT = W2T; HP = h2P; sout = s2; av = a + F_; row0 = gr - M_; isH2 = true;  }
    int fbase = w * 32;
    vf4 acc[2] = {};
    const float* xp = X + (size_t)(row0 + lr) * FIN_ + lg * 8;
#pragma unroll
    for (int kk = 0; kk < FIN_; kk += 32) {
        float4 xa = *(const float4*)(xp + kk);
        float4 xb = *(const float4*)(xp + kk + 4);
        ABu af;
        af.s[0] = (short)f2b(xa.x); af.s[1] = (short)f2b(xa.y);
        af.s[2] = (short)f2b(xa.z); af.s[3] = (short)f2b(xa.w);
        af.s[4] = (short)f2b(xb.x); af.s[5] = (short)f2b(xb.y);
        af.s[6] = (short)f2b(xb.z); af.s[7] = (short)f2b(xb.w);
#pragma unroll
        for (int q = 0; q < 2; ++q) {
            ABu bf; bf.s = *(const vs8*)(WT + (fbase + q * 16 + lr) * FIN_ + kk + lg * 8);
            acc[q] = mfma16(af, bf, acc[q]);
        }
    }
    if (isH2) {
#pragma unroll
        for (int q = 0; q < 2; ++q)
#pragma unroll
            for (int r = 0; r < 4; ++r)
                h2[(size_t)(row0 + lg * 4 + r) * F_ + fbase + q * 16 + lr] = acc[q][r];
    }
#pragma unroll
    for (int q = 0; q < 2; ++q)
#pragma unroll
        for (int r = 0; r < 4; ++r)
            tb[lg * 4 + r][fbase + q * 16 + lr] = f2b(acc[q][r]);
    float a0 = av[fbase + lr], a1 = av[fbase + 16 + lr];
    float tv[4];
#pragma unroll
    for (int r = 0; r < 4; ++r) tv[r] = acc[0][r] * a0 + acc[1][r] * a1;
#pragma unroll
    for (int off = 1; off < 16; off <<= 1)
#pragma unroll
        for (int r = 0; r < 4; ++r) tv[r] += __shfl_xor(tv[r], off, 64);
    if ((l & 15) == 0)
#pragma unroll
        for (int r = 0; r < 4; ++r) sred[w][lg * 4 + r] = tv[r];
    __syncthreads();
    {
        int f = t >> 1, half = t & 1;
        vs8 o;
#pragma unroll
        for (int j = 0; j < 8; ++j) o[j] = (short)tb[half * 8 + j][f];
        *(vs8*)(HP + ((size_t)(row0 >> 5) * 128 + f) * 32 + (row0 & 16) + half * 8) = o;
    }
    if (t < 16) {
        float s = sred[0][t] + sred[1][t] + sred[2][t] + sred[3][t];
        sout[row0 + t] = s;
    }
}

// ---- FUSED: inter stats+bitmask | city/prov bitmask+counts | h2wP gather ----
__global__ __launch_bounds__(256) void k_adjgather(const int* __restrict__ inter, const float* __restrict__ s1,
                                                   const float* __restrict__ s2, unsigned short* __restrict__ bm,
                                                   float* __restrict__ rowmax, float* __restrict__ rowinv,
                                                   const int* __restrict__ city, const int* __restrict__ prov,
                                                   const int* __restrict__ src,
                                                   uint32_t* __restrict__ BMtc, uint32_t* __restrict__ BMtp,
                                                   float* __restrict__ w3, float* __restrict__ w4,
                                                   const float* __restrict__ h2, unsigned short* __restrict__ h2wP) {
    __shared__ float wred[8];
    int t = threadIdx.x;
    int wv = t >> 6, ln = t & 63;
    if (blockIdx.x < N_) {
        int n = blockIdx.x;
        const int* rp = inter + (size_t)n * M_ + t * 16;
        float sv[16]; unsigned mask = 0;
#pragma unroll
        for (int c = 0; c < 4; ++c) {
            int4 v = *(const int4*)(rp + c * 4);
            if (v.x > 0) mask |= 1u << (c * 4 + 0);
            if (v.y > 0) mask |= 1u << (c * 4 + 1);
            if (v.z > 0) mask |= 1u << (c * 4 + 2);
            if (v.w > 0) mask |= 1u << (c * 4 + 3);
            float4 s = *(const float4*)(s1 + t * 16 + c * 4);
            sv[c * 4 + 0] = s.x; sv[c * 4 + 1] = s.y; sv[c * 4 + 2] = s.z; sv[c * 4 + 3] = s.w;
        }
        bm[(size_t)n * 256 + t] = (unsigned short)(mask & 0xffffu);
        float mx = -3.0e38f;
#pragma unroll
        for (int j = 0; j < 16; ++j) if (mask & (1u << j)) mx = fmaxf(mx, sv[j]);
        for (int off = 32; off > 0; off >>= 1) mx = fmaxf(mx, __shfl_down(mx, off, 64));
        if (ln == 0) wred[wv] = mx;
        __syncthreads();
        float s1mx = fmaxf(fmaxf(wred[0], wred[1]), fmaxf(wred[2], wred[3]));
        float s2n = s2[n];
        float rmx = lrelu(s2n + s1mx);
        float sum = 0.f;
#pragma unroll
        for (int j = 0; j < 16; ++j) if (mask & (1u << j)) sum += __expf(lrelu(s2n + sv[j]) - rmx);
        for (int off = 32; off > 0; off >>= 1) sum += __shfl_down(sum, off, 64);
        if (ln == 0) wred[4 + wv] = sum;
        __syncthreads();
        if (t == 0) {
            float tot = wred[4] + wred[5] + wred[6] + wred[7];
            bool any = s1mx > -2.9e38f;
            rowmax[n] = any ? rmx : 0.f;
            rowinv[n] = (any && tot > 0.f) ? 1.0f / tot : 0.f;
        }
    } else if (blockIdx.x < N_ + 2 * B_) {
        int bb = blockIdx.x - N_;
        int b = bb & (B_ - 1);
        bool isC = bb < B_;
        const int* adj = isC ? city : prov;
        uint32_t* BM = isC ? BMtc : BMtp;
        float* wout = isC ? w3 : w4;
        const int* rowp = adj + (size_t)src[b] * N_;
        int cnt = 0;
#pragma unroll 4
        for (int i = 0; i < N_ / 256; ++i) {
            int v = rowp[i * 256 + t];
            unsigned long long bal = __ballot(v > 0);
            cnt += (v > 0);
            if (ln == 0) {
                int widx = i * 8 + wv * 2;
                BM[(size_t)widx * B_ + b] = (uint32_t)bal;
                BM[(size_t)(widx + 1) * B_ + b] = (uint32_t)(bal >> 32);
            }
        }
        float fc = (float)cnt;
        for (int off = 32; off > 0; off >>= 1) fc += __shfl_down(fc, off, 64);
        if (ln == 0) wred[wv] = fc;
        __syncthreads();
        if (t == 0) {
            float tot = wred[0] + wred[1] + wred[2] + wred[3];
            wout[b] = tot > 0.f ? 1.0f / tot : 0.f;
        }
    } else {
        int bblk = blockIdx.x - (N_ + 2 * B_);            // 64 blocks
        int f = t & 127, halfb = t >> 7;
        vs8 o0, o1;
#pragma unroll
        for (int i = 0; i < 8; ++i) {
            int b0 = bblk * 32 + halfb * 16 + i;
            o0[i] = (short)f2b(h2[(size_t)src[b0] * F_ + f]);
            int b1 = b0 + 8;
            o1[i] = (short)f2b(h2[(size_t)src[b1] * F_ + f]);
        }
        unsigned short* dst = h2wP + ((size_t)bblk * 128 + f) * 32 + halfb * 16;
        *(vs8*)dst = o0;
        *(vs8*)(dst + 8) = o1;
    }
}

// ---- ballot bit-transpose: bm[n][m-bits] -> bmT[m][n-bits], 64x64-bit tiles (R5-verified) ----
__global__ __launch_bounds__(256) void k_bitT(const unsigned long long* __restrict__ bm64,
                                              unsigned long long* __restrict__ bmT64) {
    int tile = blockIdx.x * 4 + (threadIdx.x >> 6);       // 8192 tiles: 128 n-tiles x 64 m-tiles
    int l = threadIdx.x & 63;
    int tn = tile >> 6, tm = tile & 63;
    unsigned long long row = bm64[(size_t)(tn * 64 + l) * 64 + tm];
    unsigned long long mine = 0;
#pragma unroll
    for (int c = 0; c < 64; ++c) {
        unsigned long long b = __ballot((unsigned)((row >> c) & 1ull));
        if (l == c) mine = b;
    }
    bmT64[(size_t)(tm * 64 + l) * 128 + tn] = mine;
}

// ---- MERGED gemmA | gemmB | gemmC — att regenerated in-register from L1-resident bitmasks ----
__global__ __launch_bounds__(256) void k_gemmABC(const uint32_t* __restrict__ bm32,
                                                 const unsigned char* __restrict__ bmT8,
                                                 const float* __restrict__ s1, const float* __restrict__ s2,
                                                 const float* __restrict__ rowmax, const float* __restrict__ rowinv,
                                                 const unsigned short* __restrict__ h1P,
                                                 const unsigned short* __restrict__ h2P,
                                                 const uint32_t* __restrict__ BMtc, const uint32_t* __restrict__ BMtp,
                                                 const float* __restrict__ w3, const float* __restrict__ w4,
                                                 const unsigned short* __restrict__ h2wP,
                                                 float* __restrict__ u_in, float* __restrict__ v_in) {
    int t = threadIdx.x;
    int w = t >> 6, l = t & 63;
    int lr = l & 15, lg = l >> 4;
    int bx = blockIdx.x;
    if (bx < 1024) {
        // ---- gemmA: u_in += att @ h1.  att row-pair regen from bm32 (L1) + score vecs ----
        int xa = bx & 127, ya = bx >> 7;
        int nb0 = xa * 64 + (w & 1) * 32;
        int fb = (w >> 1) * 64;
        int n0 = nb0 + lr, n1 = nb0 + 16 + lr;
        float s20 = s2[n0], r0 = rowmax[n0], i0 = rowinv[n0];
        float s21 = s2[n1], r1 = rowmax[n1], i1 = rowinv[n1];
        vf4 acc[2][4] = {};
        for (int mblk = ya * 16; mblk < ya * 16 + 16; ++mblk) {
            uint32_t bits0 = bm32[(size_t)n0 * 128 + mblk];
            uint32_t bits1 = bm32[(size_t)n1 * 128 + mblk];
            int mm = mblk * 32 + lg * 8;
            float4 sa = *(const float4*)(s1 + mm);
            float4 sb = *(const float4*)(s1 + mm + 4);
            float sv[8] = {sa.x, sa.y, sa.z, sa.w, sb.x, sb.y, sb.z, sb.w};
            ABu af0, af1;
#pragma unroll
            for (int j = 0; j < 8; ++j) {
                int bp_ = lg * 8 + j;
                float v0 = ((bits0 >> bp_) & 1u) ? __expf(lrelu(s20 + sv[j]) - r0) * i0 : 0.f;
                float v1 = ((bits1 >> bp_) & 1u) ? __expf(lrelu(s21 + sv[j]) - r1) * i1 : 0.f;
                af0.s[j] = (short)f2b(v0);
                af1.s[j] = (short)f2b(v1);
            }
#pragma unroll
            for (int q = 0; q < 4; ++q) {
                ABu bf; bf.s = *(const vs8*)(h1P + ((size_t)mblk * 128 + fb + q * 16 + lr) * 32 + lg * 8);
                acc[0][q] = mfma16(af0, bf, acc[0][q]);
                acc[1][q] = mfma16(af1, bf, acc[1][q]);
            }
        }
#pragma unroll
        for (int s = 0; s < 2; ++s)
#pragma unroll
            for (int q = 0; q < 4; ++q)
#pragma unroll
                for (int r = 0; r < 4; ++r)
                    atomicAdd(&u_in[(size_t)(nb0 + s * 16 + lg * 4 + r) * F_ + fb + q * 16 + lr], acc[s][q][r]);
    } else if (bx < 2048) {
        // ---- gemmB: v_in += att.T @ h2.  att col regen from bmT8 (L1) + score vecs ----
        int i = bx - 1024;
        int xb = i & 127, yb = i >> 7;
        int mb = xb * 32;
        int mh = (w & 1) * 16;
        int fb = (w >> 1) * 64;
        int m = mb + mh + lr;
        float s1m = s1[m];
        const unsigned char* bp = bmT8 + (size_t)m * 1024;
        vf4 acc[4] = {};
        for (int n0 = yb * 1024; n0 < yb * 1024 + 1024; n0 += 32) {
            unsigned bits = bp[(n0 >> 3) + lg];
            int nn = n0 + lg * 8;
            float4 za = *(const float4*)(s2 + nn);
            float4 zb = *(const float4*)(s2 + nn + 4);
            float4 ra = *(const float4*)(rowmax + nn);
            float4 rb = *(const float4*)(rowmax + nn + 4);
            float4 ia = *(const float4*)(rowinv + nn);
            float4 ib = *(const float4*)(rowinv + nn + 4);
            float zv[8] = {za.x, za.y, za.z, za.w, zb.x, zb.y, zb.z, zb.w};
            float rv[8] = {ra.x, ra.y, ra.z, ra.w, rb.x, rb.y, rb.z, rb.w};
            float iv[8] = {ia.x, ia.y, ia.z, ia.w, ib.x, ib.y, ib.z, ib.w};
            ABu af;
#pragma unroll
            for (int j = 0; j < 8; ++j) {
                float v = ((bits >> j) & 1u) ? __expf(lrelu(zv[j] + s1m) - rv[j]) * iv[j] : 0.f;
                af.s[j] = (short)f2b(v);
            }
#pragma unroll
            for (int q = 0; q < 4; ++q) {
                ABu bf; bf.s = *(const vs8*)(h2P + ((size_t)(n0 >> 5) * 128 + fb + q * 16 + lr) * 32 + lg * 8);
                acc[q] = mfma16(af, bf, acc[q]);
            }
        }
#pragma unroll
        for (int q = 0; q < 4; ++q)
#pragma unroll
            for (int r = 0; r < 4; ++r)
                atomicAdd(&v_in[(size_t)(mb + mh + lg * 4 + r) * F_ + fb + q * 16 + lr], acc[q][r]);
    } else {
        // ---- gemmC: u_in += G @ h2w.  G on-the-fly from transposed city/prov bitmasks ----
        int i = bx - 2048;
        int xc = i & 127, yc = i >> 7;
        int nb0 = xc * 64 + (w & 1) * 32;                // 32-aligned -> wi uniform per wave
        int fb = (w >> 1) * 64;
        int wi = nb0 >> 5;
        const uint32_t* bc = BMtc + (size_t)wi * B_;
        const uint32_t* bp = BMtp + (size_t)wi * B_;
        vf4 acc[2][4] = {};
        int b0s = yc * (B_ / 4);
        for (int b0 = b0s; b0 < b0s + B_ / 4; b0 += 32) {
            int bb = b0 + lg * 8;
            uint4 c0 = *(const uint4*)(bc + bb);
            uint4 c1 = *(const uint4*)(bc + bb + 4);
            uint4 p0 = *(const uint4*)(bp + bb);
            uint4 p1 = *(const uint4*)(bp + bb + 4);
            float4 wa = *(const float4*)(w3 + bb);
            float4 wb = *(const float4*)(w3 + bb + 4);
            float4 wc = *(const float4*)(w4 + bb);
            float4 wd = *(const float4*)(w4 + bb + 4);
            uint32_t cw[8] = {c0.x, c0.y, c0.z, c0.w, c1.x, c1.y, c1.z, c1.w};
            uint32_t pw[8] = {p0.x, p0.y, p0.z, p0.w, p1.x, p1.y, p1.z, p1.w};
            float w3v[8] = {wa.x, wa.y, wa.z, wa.w, wb.x, wb.y, wb.z, wb.w};
            float w4v[8] = {wc.x, wc.y, wc.z, wc.w, wd.x, wd.y, wd.z, wd.w};
            ABu af0, af1;
#pragma unroll
            for (int j = 0; j < 8; ++j) {
                float v0 = (((cw[j] >> lr) & 1u) ? w3v[j] : 0.f) + (((pw[j] >> lr) & 1u) ? w4v[j] : 0.f);
                float v1 = (((cw[j] >> (16 + lr)) & 1u) ? w3v[j] : 0.f) + (((pw[j] >> (16 + lr)) & 1u) ? w4v[j] : 0.f);
                af0.s[j] = (short)f2b(v0);
                af1.s[j] = (short)f2b(v1);
            }
#pragma unroll
            for (int q = 0; q < 4; ++q) {
                ABu bf; bf.s = *(const vs8*)(h2wP + ((size_t)(b0 >> 5) * 128 + fb + q * 16 + lr) * 32 + lg * 8);
                acc[0][q] = mfma16(af0, bf, acc[0][q]);
                acc[1][q] = mfma16(af1, bf, acc[1][q]);
            }
        }
#pragma unroll
        for (int s = 0; s < 2; ++s)
#pragma unroll
            for (int q = 0; q < 4; ++q)
#pragma unroll
                for (int r = 0; r < 4; ++r)
                    atomicAdd(&u_in[(size_t)(nb0 + s * 16 + lg * 4 + r) * F_ + fb + q * 16 + lr], acc[s][q][r]);
    }
}

// ---------------- batchnorm column stats, 768 blocks (parallelism fix) ----------------
__global__ __launch_bounds__(256) void k_bnstats2(const float* __restrict__ v_in, const float* __restrict__ u_in,
                                                  float* __restrict__ stats) {
    __shared__ float r1[256], r2[256];
    int bx = blockIdx.x;
    const float* P; int R, stride; float* sum; float* sq;
    if (bx < 256) { P = v_in; R = M_; stride = 512;  sum = stats;       sq = stats + 128; }
    else          { P = u_in; R = N_; stride = 1024; sum = stats + 256; sq = stats + 384; bx -= 256; }
    int f = threadIdx.x & 127;
    int half = threadIdx.x >> 7;
    float s = 0.f, s2v = 0.f;
    for (int r = bx * 2 + half; r < R; r += stride) {
        float v = P[(size_t)r * F_ + f];
        s += v; s2v += v * v;
    }
    r1[threadIdx.x] = s; r2[threadIdx.x] = s2v;
    __syncthreads();
    if (half == 0) {
        atomicAdd(&sum[f], r1[f] + r1[f + 128]);
        atomicAdd(&sq[f], r2[f] + r2[f + 128]);
    }
}

// ---- bn finalize (per-block recompute) + apply + leaky + cast bf16, float4-vectorized ----
__global__ __launch_bounds__(256) void k_bnapplyF(const float* __restrict__ v_in, const float* __restrict__ u_in,
                                                  const float* __restrict__ stats,
                                                  const float* __restrict__ g1, const float* __restrict__ b1,
                                                  const float* __restrict__ g2, const float* __restrict__ b2,
                                                  unsigned short* __restrict__ v_outb, unsigned short* __restrict__ u_outb) {
    __shared__ float sc[256], sh[256];                    // [which*128+f]
    int t = threadIdx.x;
    {
        int which = t >> 7, f = t & 127;
        const float* sum = stats + which * 256;
        const float* sq = sum + 128;
        const float* g = which ? g2 : g1;
        const float* be = which ? b2 : b1;
        float R = which ? (float)N_ : (float)M_;
        float mean = sum[f] / R;
        float var = sq[f] / R - mean * mean;
        float s = g[f] * rsqrtf(var + 1e-5f);
        sc[t] = s; sh[t] = be[f] - mean * s;
    }
    __syncthreads();
    int id4 = blockIdx.x * 256 + t;                       // one float4 per thread
    int idx = id4 * 4;
    int which = idx >= M_ * F_;
    int rel = which ? idx - M_ * F_ : idx;
    const float* P = which ? u_in : v_in;
    unsigned short* Q = which ? u_outb : v_outb;
    int f0 = (rel & 127) + which * 128;
    float4 p = *(const float4*)(P + rel);
    ushort4 o;
    o.x = f2b(lrelu(p.x * sc[f0 + 0] + sh[f0 + 0]));
    o.y = f2b(lrelu(p.y * sc[f0 + 1] + sh[f0 + 1]));
    o.z = f2b(lrelu(p.z * sc[f0 + 2] + sh[f0 + 2]));
    o.w = f2b(lrelu(p.w * sc[f0 + 3] + sh[f0 + 3]));
    *(ushort4*)(Q + rel) = o;
}

// ---------------- out = elu(U @ V^T) ----------------
__global__ __launch_bounds__(256) void k_gemmD(const unsigned short* __restrict__ U,
                                               const unsigned short* __restrict__ V,
                                               float* __restrict__ out) {
    int w = threadIdx.x >> 6, l = threadIdx.x & 63;
    int lr = l & 15, lg = l >> 4;
    int nb = blockIdx.x * 64 + w * 16;
    int mb = blockIdx.y * 64;
    vf4 acc[4] = {};
#pragma unroll
    for (int k0 = 0; k0 < F_; k0 += 32) {
        ABu af; af.s = *(const vs8*)(U + (size_t)(nb + lr) * F_ + k0 + lg * 8);
#pragma unroll
        for (int q = 0; q < 4; ++q) {
            ABu bf; bf.s = *(const vs8*)(V + (size_t)(mb + q * 16 + lr) * F_ + k0 + lg * 8);
            acc[q] = mfma16(af, bf, acc[q]);
        }
    }
#pragma unroll
    for (int q = 0; q < 4; ++q)
#pragma unroll
        for (int r = 0; r < 4; ++r) {
            int row = nb + lg * 4 + r;
            int col = mb + q * 16 + lr;
            float x = acc[q][r];
            out[(size_t)row * M_ + col] = x > 0.f ? x : __expf(x) - 1.f;
        }
}

extern "C" void kernel_launch(void* const* d_in, const int* in_sizes, int n_in,
                              void* d_out, int out_size, void* d_ws, size_t ws_size,
                              hipStream_t stream) {
    const float* Sinput = (const float*)d_in[0];
    const float* Rinput = (const float*)d_in[1];
    const int* inter_adj = (const int*)d_in[2];
    const int* city_adj = (const int*)d_in[3];
    const int* prov_adj = (const int*)d_in[4];
    const int* src = (const int*)d_in[5];
    const float* W1 = (const float*)d_in[6];
    const float* W2 = (const float*)d_in[7];
    const float* a = (const float*)d_in[8];
    const float* g1 = (const float*)d_in[11];
    const float* b1 = (const float*)d_in[12];
    const float* g2 = (const float*)d_in[13];
    const float* b2 = (const float*)d_in[14];
    float* out = (float*)d_out;

    char* ws = (char*)d_ws;
    size_t o = 0;
    auto take = [&](size_t bytes) { char* p = ws + o; o += (bytes + 255) & ~(size_t)255; return p; };
    float* u_in = (float*)take((size_t)N_ * F_ * 4);
    float* v_in = (float*)take((size_t)M_ * F_ * 4);
    float* stats = (float*)take(512 * 4);
    size_t zero_bytes = o;                               // u_in + v_in + stats, zeroed by k_prep
    float* h2 = (float*)take((size_t)N_ * F_ * 4);
    unsigned short* h1P = (unsigned short*)take((size_t)(M_ / 32) * 128 * 32 * 2);
    unsigned short* h2P = (unsigned short*)take((size_t)(N_ / 32) * 128 * 32 * 2);
    unsigned short* W1T = (unsigned short*)take((size_t)F_ * FIN_ * 2);
    unsigned short* W2T = (unsigned short*)take((size_t)F_ * FIN_ * 2);
    float* s1 = (float*)take(M_ * 4);
    float* s2 = (float*)take(N_ * 4);
    float* rowmax = (float*)take(N_ * 4);
    float* rowinv = (float*)take(N_ * 4);
    float* w3 = (float*)take(B_ * 4);
    float* w4 = (float*)take(B_ * 4);
    unsigned short* h2wP = (unsigned short*)take((size_t)(B_ / 32) * 128 * 32 * 2);
    unsigned short* u_outb = (unsigned short*)take((size_t)N_ * F_ * 2);
    unsigned short* v_outb = (unsigned short*)take((size_t)M_ * F_ * 2);
    uint32_t* BMtc = (uint32_t*)take((size_t)256 * B_ * 4);
    uint32_t* BMtp = (uint32_t*)take((size_t)256 * B_ * 4);
    unsigned short* bm = (unsigned short*)take((size_t)N_ * 256 * 2);      // 4 MB, [n][m-bits]
    unsigned short* bmT = (unsigned short*)take((size_t)M_ * 512 * 2);     // 4 MB, [m][n-bits]
    (void)ws_size; (void)in_sizes; (void)n_in; (void)out_size;

    int nz4 = (int)(zero_bytes / 16);
    int zblocks = (nz4 + 255) / 256;
    k_prep<<<256 + zblocks, 256, 0, stream>>>(W1, W2, W1T, W2T, (float4*)d_ws, nz4);
    k_hgemmF<<<(M_ + N_) / 16, 256, 0, stream>>>(Rinput, Sinput, W1T, W2T, a, h2, h1P, h2P, s1, s2);
    k_adjgather<<<N_ + 2 * B_ + B_ / 32, 256, 0, stream>>>(inter_adj, s1, s2, bm, rowmax, rowinv,
                                                           city_adj, prov_adj, src, BMtc, BMtp, w3, w4,
                                                           h2, h2wP);
    k_bitT<<<2048, 256, 0, stream>>>((const unsigned long long*)bm, (unsigned long long*)bmT);
    k_gemmABC<<<2560, 256, 0, stream>>>((const uint32_t*)bm, (const unsigned char*)bmT,
                                        s1, s2, rowmax, rowinv, h1P, h2P,
                                        BMtc, BMtp, w3, w4, h2wP, u_in, v_in);
    k_bnstats2<<<768, 256, 0, stream>>>(v_in, u_in, stats);
    k_bnapplyF<<<(M_ + N_) * F_ / 4 / 256, 256, 0, stream>>>(v_in, u_in, stats, g1, b1, g2, b2, v_outb, u_outb);
    k_gemmD<<<dim3(N_ / 64, M_ / 64), 256, 0, stream>>>(u_outb, v_outb, out);
}

// Round 11
// 352.409 us; speedup vs baseline: 1.1061x; 1.1061x over previous
//
#include <hip/hip_runtime.h>
#include <stdint.h>

#define N_ 8192
#define M_ 4096
#define FIN_ 256
#define F_ 128
#define B_ 2048

typedef __attribute__((ext_vector_type(8))) short vs8;
typedef __attribute__((ext_vector_type(8))) __bf16 vb8;
typedef __attribute__((ext_vector_type(4))) float vf4;

union ABu { vs8 s; vb8 b; };

__device__ __forceinline__ vf4 mfma16(const ABu& a, const ABu& b, vf4 c) {
    return __builtin_amdgcn_mfma_f32_16x16x32_bf16(a.b, b.b, c, 0, 0, 0);
}
__device__ __forceinline__ unsigned short f2b(float x) {
    union { float f; unsigned u; } v; v.f = x;
    unsigned r = v.u + 0x7fffu + ((v.u >> 16) & 1u);
    return (unsigned short)(r >> 16);
}
__device__ __forceinline__ float lrelu(float x) { return x > 0.f ? x : 0.2f * x; }

// ---- prep: W[256][128] f32 -> WT[128][256] bf16  +  zero u_in/v_in/stats ----
__global__ void k_prep(const float* __restrict__ W1, const float* __restrict__ W2,
                       unsigned short* __restrict__ W1T, unsigned short* __restrict__ W2T,
                       float4* __restrict__ Z, int nz4) {
    int id = blockIdx.x * 256 + threadIdx.x;
    if (id < 65536) {
        const float* W = (id < 32768) ? W1 : W2;
        unsigned short* WT = (id < 32768) ? W1T : W2T;
        int o = id & 32767;
        int f = o >> 8, k = o & 255;
        WT[o] = f2b(W[k * F_ + f]);
    } else {
        int z = id - 65536;
        if (z < nz4) Z[z] = make_float4(0.f, 0.f, 0.f, 0.f);
    }
}

// ---- FUSED: h = X@W (MFMA); write h2 f32, packed hP[kblk][f][32] bf16, s1/s2 row-dots ----
__global__ __launch_bounds__(256) void k_hgemmF(const float* __restrict__ Rin, const float* __restrict__ Sin,
                                                const unsigned short* __restrict__ W1T,
                                                const unsigned short* __restrict__ W2T,
                                                const float* __restrict__ a,
                                                float* __restrict__ h2,
                                                unsigned short* __restrict__ h1P, unsigned short* __restrict__ h2P,
                                                float* __restrict__ s1, float* __restrict__ s2) {
    __shared__ unsigned short tb[16][136];               // 16 rows x 128 f, padded
    __shared__ float sred[4][16];
    int t = threadIdx.x;
    int w = t >> 6, l = t & 63, lr = l & 15, lg = l >> 4;
    int gr = blockIdx.x * 16;
    const float* X; const unsigned short* WT; unsigned short* HP; float* sout; const float* av;
    int row0; bool isH2;
    if (gr < M_) { X = Rin; WT = W1T; HP = h1P; sout = s1; av = a;      row0 = gr;      isH2 = false; }
    else         { X = Sin; WT = W2T; HP = h2P; sout = s2; av = a + F_; row0 = gr - M_; isH2 = true;  }
    int fbase = w * 32;
    vf4 acc[2] = {};
    const float* xp = X + (size_t)(row0 + lr) * FIN_ + lg * 8;
#pragma unroll
    for (int kk = 0; kk < FIN_; kk += 32) {
        float4 xa = *(const float4*)(xp + kk);
        float4 xb = *(const float4*)(xp + kk + 4);
        ABu af;
        af.s[0] = (short)f2b(xa.x); af.s[1] = (short)f2b(xa.y);
        af.s[2] = (short)f2b(xa.z); af.s[3] = (short)f2b(xa.w);
        af.s[4] = (short)f2b(xb.x); af.s[5] = (short)f2b(xb.y);
        af.s[6] = (short)f2b(xb.z); af.s[7] = (short)f2b(xb.w);
#pragma unroll
        for (int q = 0; q < 2; ++q) {
            ABu bf; bf.s = *(const vs8*)(WT + (fbase + q * 16 + lr) * FIN_ + kk + lg * 8);
            acc[q] = mfma16(af, bf, acc[q]);
        }
    }
    if (isH2) {
#pragma unroll
        for (int q = 0; q < 2; ++q)
#pragma unroll
            for (int r = 0; r < 4; ++r)
                h2[(size_t)(row0 + lg * 4 + r) * F_ + fbase + q * 16 + lr] = acc[q][r];
    }
#pragma unroll
    for (int q = 0; q < 2; ++q)
#pragma unroll
        for (int r = 0; r < 4; ++r)
            tb[lg * 4 + r][fbase + q * 16 + lr] = f2b(acc[q][r]);
    float a0 = av[fbase + lr], a1 = av[fbase + 16 + lr];
    float tv[4];
#pragma unroll
    for (int r = 0; r < 4; ++r) tv[r] = acc[0][r] * a0 + acc[1][r] * a1;
#pragma unroll
    for (int off = 1; off < 16; off <<= 1)
#pragma unroll
        for (int r = 0; r < 4; ++r) tv[r] += __shfl_xor(tv[r], off, 64);
    if ((l & 15) == 0)
#pragma unroll
        for (int r = 0; r < 4; ++r) sred[w][lg * 4 + r] = tv[r];
    __syncthreads();
    {
        int f = t >> 1, half = t & 1;
        vs8 o;
#pragma unroll
        for (int j = 0; j < 8; ++j) o[j] = (short)tb[half * 8 + j][f];
        *(vs8*)(HP + ((size_t)(row0 >> 5) * 128 + f) * 32 + (row0 & 16) + half * 8) = o;
    }
    if (t < 16) {
        float s = sred[0][t] + sred[1][t] + sred[2][t] + sred[3][t];
        sout[row0 + t] = s;
    }
}

// ---- FUSED: inter stats+bitmask | city/prov bitmask+counts | h2wP gather ----
__global__ __launch_bounds__(256) void k_adjgather(const int* __restrict__ inter, const float* __restrict__ s1,
                                                   const float* __restrict__ s2, unsigned short* __restrict__ bm,
                                                   float* __restrict__ rowmax, float* __restrict__ rowinv,
                                                   const int* __restrict__ city, const int* __restrict__ prov,
                                                   const int* __restrict__ src,
                                                   uint32_t* __restrict__ BMtc, uint32_t* __restrict__ BMtp,
                                                   float* __restrict__ w3, float* __restrict__ w4,
                                                   const float* __restrict__ h2, unsigned short* __restrict__ h2wP) {
    __shared__ float wred[8];
    int t = threadIdx.x;
    int wv = t >> 6, ln = t & 63;
    if (blockIdx.x < N_) {
        int n = blockIdx.x;
        const int* rp = inter + (size_t)n * M_ + t * 16;
        float sv[16]; unsigned mask = 0;
#pragma unroll
        for (int c = 0; c < 4; ++c) {
            int4 v = *(const int4*)(rp + c * 4);
            if (v.x > 0) mask |= 1u << (c * 4 + 0);
            if (v.y > 0) mask |= 1u << (c * 4 + 1);
            if (v.z > 0) mask |= 1u << (c * 4 + 2);
            if (v.w > 0) mask |= 1u << (c * 4 + 3);
            float4 s = *(const float4*)(s1 + t * 16 + c * 4);
            sv[c * 4 + 0] = s.x; sv[c * 4 + 1] = s.y; sv[c * 4 + 2] = s.z; sv[c * 4 + 3] = s.w;
        }
        bm[(size_t)n * 256 + t] = (unsigned short)(mask & 0xffffu);
        float mx = -3.0e38f;
#pragma unroll
        for (int j = 0; j < 16; ++j) if (mask & (1u << j)) mx = fmaxf(mx, sv[j]);
        for (int off = 32; off > 0; off >>= 1) mx = fmaxf(mx, __shfl_down(mx, off, 64));
        if (ln == 0) wred[wv] = mx;
        __syncthreads();
        float s1mx = fmaxf(fmaxf(wred[0], wred[1]), fmaxf(wred[2], wred[3]));
        float s2n = s2[n];
        float rmx = lrelu(s2n + s1mx);
        float sum = 0.f;
#pragma unroll
        for (int j = 0; j < 16; ++j) if (mask & (1u << j)) sum += __expf(lrelu(s2n + sv[j]) - rmx);
        for (int off = 32; off > 0; off >>= 1) sum += __shfl_down(sum, off, 64);
        if (ln == 0) wred[4 + wv] = sum;
        __syncthreads();
        if (t == 0) {
            float tot = wred[4] + wred[5] + wred[6] + wred[7];
            bool any = s1mx > -2.9e38f;
            rowmax[n] = any ? rmx : 0.f;
            rowinv[n] = (any && tot > 0.f) ? 1.0f / tot : 0.f;
        }
    } else if (blockIdx.x < N_ + 2 * B_) {
        int bb = blockIdx.x - N_;
        int b = bb & (B_ - 1);
        bool isC = bb < B_;
        const int* adj = isC ? city : prov;
        uint32_t* BM = isC ? BMtc : BMtp;
        float* wout = isC ? w3 : w4;
        const int* rowp = adj + (size_t)src[b] * N_;
        int cnt = 0;
#pragma unroll 4
        for (int i = 0; i < N_ / 256; ++i) {
            int v = rowp[i * 256 + t];
            unsigned long long bal = __ballot(v > 0);
            cnt += (v > 0);
            if (ln == 0) {
                int widx = i * 8 + wv * 2;
                BM[(size_t)widx * B_ + b] = (uint32_t)bal;
                BM[(size_t)(widx + 1) * B_ + b] = (uint32_t)(bal >> 32);
            }
        }
        float fc = (float)cnt;
        for (int off = 32; off > 0; off >>= 1) fc += __shfl_down(fc, off, 64);
        if (ln == 0) wred[wv] = fc;
        __syncthreads();
        if (t == 0) {
            float tot = wred[0] + wred[1] + wred[2] + wred[3];
            wout[b] = tot > 0.f ? 1.0f / tot : 0.f;
        }
    } else {
        int bblk = blockIdx.x - (N_ + 2 * B_);            // 64 blocks
        int f = t & 127, halfb = t >> 7;
        vs8 o0, o1;
#pragma unroll
        for (int i = 0; i < 8; ++i) {
            int b0 = bblk * 32 + halfb * 16 + i;
            o0[i] = (short)f2b(h2[(size_t)src[b0] * F_ + f]);
            int b1 = b0 + 8;
            o1[i] = (short)f2b(h2[(size_t)src[b1] * F_ + f]);
        }
        unsigned short* dst = h2wP + ((size_t)bblk * 128 + f) * 32 + halfb * 16;
        *(vs8*)dst = o0;
        *(vs8*)(dst + 8) = o1;
    }
}

// ---- materialize att: packed attP[mblk][n][m&31] AND transposed attT[nblk][m][n&31] ----
__global__ __launch_bounds__(256) void k_attmat2(const unsigned char* __restrict__ bm8,
                                                 const float* __restrict__ s1, const float* __restrict__ s2,
                                                 const float* __restrict__ rowmax, const float* __restrict__ rowinv,
                                                 unsigned short* __restrict__ attP,
                                                 unsigned short* __restrict__ attT) {
    __shared__ unsigned short tile[64][33];              // [m_local][n_local], padded
    int bx = blockIdx.x;                                 // 16384 = (M/64) x (N/32)
    int mt = bx & 63, nt = bx >> 6;
    int nb = nt * 32, mb = mt * 64;
    int t = threadIdx.x;
    int nl = t & 31, mo = t >> 5;                        // mo 0..7
    int n = nb + nl;
    int m = mb + mo * 8;
    unsigned bits = bm8[(size_t)n * 512 + (m >> 3)];
    float s2n = s2[n], rmx = rowmax[n], rin = rowinv[n];
    float4 sa = *(const float4*)(s1 + m);
    float4 sb = *(const float4*)(s1 + m + 4);
    float sv[8] = {sa.x, sa.y, sa.z, sa.w, sb.x, sb.y, sb.z, sb.w};
    vs8 o;
#pragma unroll
    for (int j = 0; j < 8; ++j) {
        float v = (bits & (1u << j)) ? __expf(lrelu(s2n + sv[j]) - rmx) * rin : 0.f;
        o[j] = (short)f2b(v);
        tile[mo * 8 + j][nl] = (unsigned short)o[j];
    }
    *(vs8*)(attP + ((size_t)(m >> 5) * N_ + n) * 32 + (m & 31)) = o;
    __syncthreads();
    int mr = t >> 2, sg = t & 3;                         // mr 0..63, sg 0..3
    vs8 ot;
#pragma unroll
    for (int j = 0; j < 8; ++j) ot[j] = (short)tile[mr][sg * 8 + j];
    *(vs8*)(attT + ((size_t)nt * M_ + mb + mr) * 32 + sg * 8) = ot;
}

// ---- MERGED gemmA | gemmB | gemmC — distinct B-regs + A-prefetch (MLP fix) ----
__global__ __launch_bounds__(256) void k_gemmABC(const unsigned short* __restrict__ attP,
                                                 const unsigned short* __restrict__ attT,
                                                 const unsigned short* __restrict__ h1P,
                                                 const unsigned short* __restrict__ h2P,
                                                 const uint32_t* __restrict__ BMtc, const uint32_t* __restrict__ BMtp,
                                                 const float* __restrict__ w3, const float* __restrict__ w4,
                                                 const unsigned short* __restrict__ h2wP,
                                                 float* __restrict__ u_in, float* __restrict__ v_in) {
    int t = threadIdx.x;
    int w = t >> 6, l = t & 63;
    int lr = l & 15, lg = l >> 4;
    int bx = blockIdx.x;
    if (bx < 1024) {
        // gemmA (bx<512): u_in += att @ h1, A-src attP, B-src h1P, K=M
        // gemmB (bx>=512): v_in += att.T @ h2, A-src attT, B-src h2P, K=N  (identical shape)
        bool isA = bx < 512;
        int i = isA ? bx : bx - 512;
        int x, y, nsteps, kbase;
        const unsigned short* Asrc; const unsigned short* Bsrc; float* Out;
        if (isA) { x = i & 127; y = i >> 7; nsteps = 32; kbase = y * 32;      // 128 x 4, K=128 mblks
                   Asrc = attP; Bsrc = h1P; Out = u_in; }
        else     { x = i & 63;  y = i >> 6; nsteps = 32; kbase = y * 32;      // 64 x 8, K=256 nblks
                   Asrc = attT; Bsrc = h2P; Out = v_in; }
        int rb0 = x * 64 + (w & 1) * 32;                 // output-row base (n for A, m for B)
        int fb = (w >> 1) * 64;
        vf4 acc[2][4] = {};
        int rowsK = isA ? N_ : M_;                       // rows per k-block in Asrc
        size_t aoff = (size_t)(rb0 + lr) * 32 + lg * 8;
        const unsigned short* apm = Asrc + (size_t)kbase * rowsK * 32 + aoff;
        size_t astride = (size_t)rowsK * 32;
        ABu a0, a1;
        a0.s = *(const vs8*)apm;
        a1.s = *(const vs8*)(apm + 16 * 32);
        for (int it = 0; it < 32; ++it) {
            const unsigned short* hb = Bsrc + (size_t)(kbase + it) * 128 * 32;
            ABu b0, b1, b2, b3;
            b0.s = *(const vs8*)(hb + (size_t)(fb + lr) * 32 + lg * 8);
            b1.s = *(const vs8*)(hb + (size_t)(fb + 16 + lr) * 32 + lg * 8);
            b2.s = *(const vs8*)(hb + (size_t)(fb + 32 + lr) * 32 + lg * 8);
            b3.s = *(const vs8*)(hb + (size_t)(fb + 48 + lr) * 32 + lg * 8);
            const unsigned short* apn = apm + (it < 31 ? astride : 0);
            ABu a0n, a1n;
            a0n.s = *(const vs8*)apn;
            a1n.s = *(const vs8*)(apn + 16 * 32);
            acc[0][0] = mfma16(a0, b0, acc[0][0]);
            acc[1][0] = mfma16(a1, b0, acc[1][0]);
            acc[0][1] = mfma16(a0, b1, acc[0][1]);
            acc[1][1] = mfma16(a1, b1, acc[1][1]);
            acc[0][2] = mfma16(a0, b2, acc[0][2]);
            acc[1][2] = mfma16(a1, b2, acc[1][2]);
            acc[0][3] = mfma16(a0, b3, acc[0][3]);
            acc[1][3] = mfma16(a1, b3, acc[1][3]);
            a0 = a0n; a1 = a1n;
            apm = apn;
        }
#pragma unroll
        for (int s = 0; s < 2; ++s)
#pragma unroll
            for (int q = 0; q < 4; ++q)
#pragma unroll
                for (int r = 0; r < 4; ++r)
                    atomicAdd(&Out[(size_t)(rb0 + s * 16 + lg * 4 + r) * F_ + fb + q * 16 + lr], acc[s][q][r]);
    } else {
        // ---- gemmC: u_in += G @ h2w.  G on-the-fly from transposed city/prov bitmasks ----
        int i = bx - 1024;
        int xc = i & 127, yc = i >> 7;                   // 128 x 4
        int nb0 = xc * 64 + (w & 1) * 32;                // 32-aligned -> wi uniform per wave
        int fb = (w >> 1) * 64;
        int wi = nb0 >> 5;
        const uint32_t* bc = BMtc + (size_t)wi * B_;
        const uint32_t* bp = BMtp + (size_t)wi * B_;
        vf4 acc[2][4] = {};
        int b0s = yc * (B_ / 4);
        for (int b0 = b0s; b0 < b0s + B_ / 4; b0 += 32) {
            int bb = b0 + lg * 8;
            uint4 c0 = *(const uint4*)(bc + bb);
            uint4 c1 = *(const uint4*)(bc + bb + 4);
            uint4 p0 = *(const uint4*)(bp + bb);
            uint4 p1 = *(const uint4*)(bp + bb + 4);
            float4 wa = *(const float4*)(w3 + bb);
            float4 wb = *(const float4*)(w3 + bb + 4);
            float4 wc = *(const float4*)(w4 + bb);
            float4 wd = *(const float4*)(w4 + bb + 4);
            const unsigned short* hb = h2wP + (size_t)(b0 >> 5) * 128 * 32;
            ABu bf0, bf1, bf2, bf3;
            bf0.s = *(const vs8*)(hb + (size_t)(fb + lr) * 32 + lg * 8);
            bf1.s = *(const vs8*)(hb + (size_t)(fb + 16 + lr) * 32 + lg * 8);
            bf2.s = *(const vs8*)(hb + (size_t)(fb + 32 + lr) * 32 + lg * 8);
            bf3.s = *(const vs8*)(hb + (size_t)(fb + 48 + lr) * 32 + lg * 8);
            uint32_t cw[8] = {c0.x, c0.y, c0.z, c0.w, c1.x, c1.y, c1.z, c1.w};
            uint32_t pw[8] = {p0.x, p0.y, p0.z, p0.w, p1.x, p1.y, p1.z, p1.w};
            float w3v[8] = {wa.x, wa.y, wa.z, wa.w, wb.x, wb.y, wb.z, wb.w};
            float w4v[8] = {wc.x, wc.y, wc.z, wc.w, wd.x, wd.y, wd.z, wd.w};
            ABu af0, af1;
#pragma unroll
            for (int j = 0; j < 8; ++j) {
                float v0 = (((cw[j] >> lr) & 1u) ? w3v[j] : 0.f) + (((pw[j] >> lr) & 1u) ? w4v[j] : 0.f);
                float v1 = (((cw[j] >> (16 + lr)) & 1u) ? w3v[j] : 0.f) + (((pw[j] >> (16 + lr)) & 1u) ? w4v[j] : 0.f);
                af0.s[j] = (short)f2b(v0);
                af1.s[j] = (short)f2b(v1);
            }
            acc[0][0] = mfma16(af0, bf0, acc[0][0]);
            acc[1][0] = mfma16(af1, bf0, acc[1][0]);
            acc[0][1] = mfma16(af0, bf1, acc[0][1]);
            acc[1][1] = mfma16(af1, bf1, acc[1][1]);
            acc[0][2] = mfma16(af0, bf2, acc[0][2]);
            acc[1][2] = mfma16(af1, bf2, acc[1][2]);
            acc[0][3] = mfma16(af0, bf3, acc[0][3]);
            acc[1][3] = mfma16(af1, bf3, acc[1][3]);
        }
#pragma unroll
        for (int s = 0; s < 2; ++s)
#pragma unroll
            for (int q = 0; q < 4; ++q)
#pragma unroll
                for (int r = 0; r < 4; ++r)
                    atomicAdd(&u_in[(size_t)(nb0 + s * 16 + lg * 4 + r) * F_ + fb + q * 16 + lr], acc[s][q][r]);
    }
}

// ---------------- batchnorm column stats, 768 blocks ----------------
__global__ __launch_bounds__(256) void k_bnstats2(const float* __restrict__ v_in, const float* __restrict__ u_in,
                                                  float* __restrict__ stats) {
    __shared__ float r1[256], r2[256];
    int bx = blockIdx.x;
    const float* P; int R, stride; float* sum; float* sq;
    if (bx < 256) { P = v_in; R = M_; stride = 512;  sum = stats;       sq = stats + 128; }
    else          { P = u_in; R = N_; stride = 1024; sum = stats + 256; sq = stats + 384; bx -= 256; }
    int f = threadIdx.x & 127;
    int half = threadIdx.x >> 7;
    float s = 0.f, s2v = 0.f;
    for (int r = bx * 2 + half; r < R; r += stride) {
        float v = P[(size_t)r * F_ + f];
        s += v; s2v += v * v;
    }
    r1[threadIdx.x] = s; r2[threadIdx.x] = s2v;
    __syncthreads();
    if (half == 0) {
        atomicAdd(&sum[f], r1[f] + r1[f + 128]);
        atomicAdd(&sq[f], r2[f] + r2[f + 128]);
    }
}

// ---- bn finalize (per-block recompute) + apply + leaky + cast bf16, float4-vectorized ----
__global__ __launch_bounds__(256) void k_bnapplyF(const float* __restrict__ v_in, const float* __restrict__ u_in,
                                                  const float* __restrict__ stats,
                                                  const float* __restrict__ g1, const float* __restrict__ b1,
                                                  const float* __restrict__ g2, const float* __restrict__ b2,
                                                  unsigned short* __restrict__ v_outb, unsigned short* __restrict__ u_outb) {
    __shared__ float sc[256], sh[256];                    // [which*128+f]
    int t = threadIdx.x;
    {
        int which = t >> 7, f = t & 127;
        const float* sum = stats + which * 256;
        const float* sq = sum + 128;
        const float* g = which ? g2 : g1;
        const float* be = which ? b2 : b1;
        float R = which ? (float)N_ : (float)M_;
        float mean = sum[f] / R;
        float var = sq[f] / R - mean * mean;
        float s = g[f] * rsqrtf(var + 1e-5f);
        sc[t] = s; sh[t] = be[f] - mean * s;
    }
    __syncthreads();
    int id4 = blockIdx.x * 256 + t;                       // one float4 per thread
    int idx = id4 * 4;
    int which = idx >= M_ * F_;
    int rel = which ? idx - M_ * F_ : idx;
    const float* P = which ? u_in : v_in;
    unsigned short* Q = which ? u_outb : v_outb;
    int f0 = (rel & 127) + which * 128;
    float4 p = *(const float4*)(P + rel);
    ushort4 o;
    o.x = f2b(lrelu(p.x * sc[f0 + 0] + sh[f0 + 0]));
    o.y = f2b(lrelu(p.y * sc[f0 + 1] + sh[f0 + 1]));
    o.z = f2b(lrelu(p.z * sc[f0 + 2] + sh[f0 + 2]));
    o.w = f2b(lrelu(p.w * sc[f0 + 3] + sh[f0 + 3]));
    *(ushort4*)(Q + rel) = o;
}

// ---------------- out = elu(U @ V^T) ----------------
__global__ __launch_bounds__(256) void k_gemmD(const unsigned short* __restrict__ U,
                                               const unsigned short* __restrict__ V,
                                               float* __restrict__ out) {
    int w = threadIdx.x >> 6, l = threadIdx.x & 63;
    int lr = l & 15, lg = l >> 4;
    int nb = blockIdx.x * 64 + w * 16;
    int mb = blockIdx.y * 64;
    vf4 acc[4] = {};
#pragma unroll
    for (int k0 = 0; k0 < F_; k0 += 32) {
        ABu af; af.s = *(const vs8*)(U + (size_t)(nb + lr) * F_ + k0 + lg * 8);
#pragma unroll
        for (int q = 0; q < 4; ++q) {
            ABu bf; bf.s = *(const vs8*)(V + (size_t)(mb + q * 16 + lr) * F_ + k0 + lg * 8);
            acc[q] = mfma16(af, bf, acc[q]);
        }
    }
#pragma unroll
    for (int q = 0; q < 4; ++q)
#pragma unroll
        for (int r = 0; r < 4; ++r) {
            int row = nb + lg * 4 + r;
            int col = mb + q * 16 + lr;
            float x = acc[q][r];
            out[(size_t)row * M_ + col] = x > 0.f ? x : __expf(x) - 1.f;
        }
}

extern "C" void kernel_launch(void* const* d_in, const int* in_sizes, int n_in,
                              void* d_out, int out_size, void* d_ws, size_t ws_size,
                              hipStream_t stream) {
    const float* Sinput = (const float*)d_in[0];
    const float* Rinput = (const float*)d_in[1];
    const int* inter_adj = (const int*)d_in[2];
    const int* city_adj = (const int*)d_in[3];
    const int* prov_adj = (const int*)d_in[4];
    const int* src = (const int*)d_in[5];
    const float* W1 = (const float*)d_in[6];
    const float* W2 = (const float*)d_in[7];
    const float* a = (const float*)d_in[8];
    const float* g1 = (const float*)d_in[11];
    const float* b1 = (const float*)d_in[12];
    const float* g2 = (const float*)d_in[13];
    const float* b2 = (const float*)d_in[14];
    float* out = (float*)d_out;

    char* ws = (char*)d_ws;
    size_t o = 0;
    auto take = [&](size_t bytes) { char* p = ws + o; o += (bytes + 255) & ~(size_t)255; return p; };
    float* u_in = (float*)take((size_t)N_ * F_ * 4);
    float* v_in = (float*)take((size_t)M_ * F_ * 4);
    float* stats = (float*)take(512 * 4);
    size_t zero_bytes = o;                               // u_in + v_in + stats, zeroed by k_prep
    float* h2 = (float*)take((size_t)N_ * F_ * 4);
    unsigned short* h1P = (unsigned short*)take((size_t)(M_ / 32) * 128 * 32 * 2);
    unsigned short* h2P = (unsigned short*)take((size_t)(N_ / 32) * 128 * 32 * 2);
    unsigned short* W1T = (unsigned short*)take((size_t)F_ * FIN_ * 2);
    unsigned short* W2T = (unsigned short*)take((size_t)F_ * FIN_ * 2);
    float* s1 = (float*)take(M_ * 4);
    float* s2 = (float*)take(N_ * 4);
    float* rowmax = (float*)take(N_ * 4);
    float* rowinv = (float*)take(N_ * 4);
    float* w3 = (float*)take(B_ * 4);
    float* w4 = (float*)take(B_ * 4);
    unsigned short* h2wP = (unsigned short*)take((size_t)(B_ / 32) * 128 * 32 * 2);
    unsigned short* u_outb = (unsigned short*)take((size_t)N_ * F_ * 2);
    unsigned short* v_outb = (unsigned short*)take((size_t)M_ * F_ * 2);
    uint32_t* BMtc = (uint32_t*)take((size_t)256 * B_ * 4);
    uint32_t* BMtp = (uint32_t*)take((size_t)256 * B_ * 4);
    unsigned short* bm = (unsigned short*)take((size_t)N_ * 256 * 2);      // 4 MB, [n][m-bits]
    unsigned short* attP = (unsigned short*)take((size_t)N_ * M_ * 2);     // 64 MB packed
    unsigned short* attT = (unsigned short*)take((size_t)N_ * M_ * 2);     // 64 MB transposed-packed
    (void)ws_size; (void)in_sizes; (void)n_in; (void)out_size;

    int nz4 = (int)(zero_bytes / 16);
    int zblocks = (nz4 + 255) / 256;
    k_prep<<<256 + zblocks, 256, 0, stream>>>(W1, W2, W1T, W2T, (float4*)d_ws, nz4);
    k_hgemmF<<<(M_ + N_) / 16, 256, 0, stream>>>(Rinput, Sinput, W1T, W2T, a, h2, h1P, h2P, s1, s2);
    k_adjgather<<<N_ + 2 * B_ + B_ / 32, 256, 0, stream>>>(inter_adj, s1, s2, bm, rowmax, rowinv,
                                                           city_adj, prov_adj, src, BMtc, BMtp, w3, w4,
                                                           h2, h2wP);
    k_attmat2<<<16384, 256, 0, stream>>>((const unsigned char*)bm, s1, s2, rowmax, rowinv, attP, attT);
    k_gemmABC<<<1536, 256, 0, stream>>>(attP, attT, h1P, h2P, BMtc, BMtp, w3, w4, h2wP, u_in, v_in);
    k_bnstats2<<<768, 256, 0, stream>>>(v_in, u_in, stats);
    k_bnapplyF<<<(M_ + N_) * F_ / 4 / 256, 256, 0, stream>>>(v_in, u_in, stats, g1, b1, g2, b2, v_outb, u_outb);
    k_gemmD<<<dim3(N_ / 64, M_ / 64), 256, 0, stream>>>(u_outb, v_outb, out);
}

// Round 12
// 347.779 us; speedup vs baseline: 1.1208x; 1.0133x over previous
//
#include <hip/hip_runtime.h>
#include <stdint.h>

#define N_ 8192
#define M_ 4096
#define FIN_ 256
#define F_ 128
#define B_ 2048

typedef __attribute__((ext_vector_type(8))) short vs8;
typedef __attribute__((ext_vector_type(8))) __bf16 vb8;
typedef __attribute__((ext_vector_type(4))) float vf4;

union ABu { vs8 s; vb8 b; };

__device__ __forceinline__ vf4 mfma16(const ABu& a, const ABu& b, vf4 c) {
    return __builtin_amdgcn_mfma_f32_16x16x32_bf16(a.b, b.b, c, 0, 0, 0);
}
__device__ __forceinline__ unsigned short f2b(float x) {
    union { float f; unsigned u; } v; v.f = x;
    unsigned r = v.u + 0x7fffu + ((v.u >> 16) & 1u);
    return (unsigned short)(r >> 16);
}
__device__ __forceinline__ float lrelu(float x) { return x > 0.f ? x : 0.2f * x; }

// ---- prep: W[256][128] f32 -> WT[128][256] bf16  +  zero stats (2KB only) ----
__global__ void k_prep(const float* __restrict__ W1, const float* __restrict__ W2,
                       unsigned short* __restrict__ W1T, unsigned short* __restrict__ W2T,
                       float4* __restrict__ Z, int nz4) {
    int id = blockIdx.x * 256 + threadIdx.x;
    if (id < 65536) {
        const float* W = (id < 32768) ? W1 : W2;
        unsigned short* WT = (id < 32768) ? W1T : W2T;
        int o = id & 32767;
        int f = o >> 8, k = o & 255;
        WT[o] = f2b(W[k * F_ + f]);
    } else {
        int z = id - 65536;
        if (z < nz4) Z[z] = make_float4(0.f, 0.f, 0.f, 0.f);
    }
}

// ---- FUSED: h = X@W (MFMA); write h2 f32, packed hP[kblk][f][32] bf16, s1/s2 row-dots ----
__global__ __launch_bounds__(256) void k_hgemmF(const float* __restrict__ Rin, const float* __restrict__ Sin,
                                                const unsigned short* __restrict__ W1T,
                                                const unsigned short* __restrict__ W2T,
                                                const float* __restrict__ a,
                                                float* __restrict__ h2,
                                                unsigned short* __restrict__ h1P, unsigned short* __restrict__ h2P,
                                                float* __restrict__ s1, float* __restrict__ s2) {
    __shared__ unsigned short tb[16][136];               // 16 rows x 128 f, padded
    __shared__ float sred[4][16];
    int t = threadIdx.x;
    int w = t >> 6, l = t & 63, lr = l & 15, lg = l >> 4;
    int gr = blockIdx.x * 16;
    const float* X; const unsigned short* WT; unsigned short* HP; float* sout; const float* av;
    int row0; bool isH2;
    if (gr < M_) { X = Rin; WT = W1T; HP = h1P; sout = s1; av = a;      row0 = gr;      isH2 = false; }
    else         { X = Sin; WT = W2T; HP = h2P; sout = s2; av = a + F_; row0 = gr - M_; isH2 = true;  }
    int fbase = w * 32;
    vf4 acc[2] = {};
    const float* xp = X + (size_t)(row0 + lr) * FIN_ + lg * 8;
#pragma unroll
    for (int kk = 0; kk < FIN_; kk += 32) {
        float4 xa = *(const float4*)(xp + kk);
        float4 xb = *(const float4*)(xp + kk + 4);
        ABu af;
        af.s[0] = (short)f2b(xa.x); af.s[1] = (short)f2b(xa.y);
        af.s[2] = (short)f2b(xa.z); af.s[3] = (short)f2b(xa.w);
        af.s[4] = (short)f2b(xb.x); af.s[5] = (short)f2b(xb.y);
        af.s[6] = (short)f2b(xb.z); af.s[7] = (short)f2b(xb.w);
#pragma unroll
        for (int q = 0; q < 2; ++q) {
            ABu bf; bf.s = *(const vs8*)(WT + (fbase + q * 16 + lr) * FIN_ + kk + lg * 8);
            acc[q] = mfma16(af, bf, acc[q]);
        }
    }
    if (isH2) {
#pragma unroll
        for (int q = 0; q < 2; ++q)
#pragma unroll
            for (int r = 0; r < 4; ++r)
                h2[(size_t)(row0 + lg * 4 + r) * F_ + fbase + q * 16 + lr] = acc[q][r];
    }
#pragma unroll
    for (int q = 0; q < 2; ++q)
#pragma unroll
        for (int r = 0; r < 4; ++r)
            tb[lg * 4 + r][fbase + q * 16 + lr] = f2b(acc[q][r]);
    float a0 = av[fbase + lr], a1 = av[fbase + 16 + lr];
    float tv[4];
#pragma unroll
    for (int r = 0; r < 4; ++r) tv[r] = acc[0][r] * a0 + acc[1][r] * a1;
#pragma unroll
    for (int off = 1; off < 16; off <<= 1)
#pragma unroll
        for (int r = 0; r < 4; ++r) tv[r] += __shfl_xor(tv[r], off, 64);
    if ((l & 15) == 0)
#pragma unroll
        for (int r = 0; r < 4; ++r) sred[w][lg * 4 + r] = tv[r];
    __syncthreads();
    {
        int f = t >> 1, half = t & 1;
        vs8 o;
#pragma unroll
        for (int j = 0; j < 8; ++j) o[j] = (short)tb[half * 8 + j][f];
        *(vs8*)(HP + ((size_t)(row0 >> 5) * 128 + f) * 32 + (row0 & 16) + half * 8) = o;
    }
    if (t < 16) {
        float s = sred[0][t] + sred[1][t] + sred[2][t] + sred[3][t];
        sout[row0 + t] = s;
    }
}

// ---- FUSED: inter stats+bitmask | city/prov bitmask+counts | h2wP gather ----
__global__ __launch_bounds__(256) void k_adjgather(const int* __restrict__ inter, const float* __restrict__ s1,
                                                   const float* __restrict__ s2, unsigned short* __restrict__ bm,
                                                   float* __restrict__ rowmax, float* __restrict__ rowinv,
                                                   const int* __restrict__ city, const int* __restrict__ prov,
                                                   const int* __restrict__ src,
                                                   uint32_t* __restrict__ BMtc, uint32_t* __restrict__ BMtp,
                                                   float* __restrict__ w3, float* __restrict__ w4,
                                                   const float* __restrict__ h2, unsigned short* __restrict__ h2wP) {
    __shared__ float wred[8];
    int t = threadIdx.x;
    int wv = t >> 6, ln = t & 63;
    if (blockIdx.x < N_) {
        int n = blockIdx.x;
        const int* rp = inter + (size_t)n * M_ + t * 16;
        float sv[16]; unsigned mask = 0;
#pragma unroll
        for (int c = 0; c < 4; ++c) {
            int4 v = *(const int4*)(rp + c * 4);
            if (v.x > 0) mask |= 1u << (c * 4 + 0);
            if (v.y > 0) mask |= 1u << (c * 4 + 1);
            if (v.z > 0) mask |= 1u << (c * 4 + 2);
            if (v.w > 0) mask |= 1u << (c * 4 + 3);
            float4 s = *(const float4*)(s1 + t * 16 + c * 4);
            sv[c * 4 + 0] = s.x; sv[c * 4 + 1] = s.y; sv[c * 4 + 2] = s.z; sv[c * 4 + 3] = s.w;
        }
        bm[(size_t)n * 256 + t] = (unsigned short)(mask & 0xffffu);
        float mx = -3.0e38f;
#pragma unroll
        for (int j = 0; j < 16; ++j) if (mask & (1u << j)) mx = fmaxf(mx, sv[j]);
        for (int off = 32; off > 0; off >>= 1) mx = fmaxf(mx, __shfl_down(mx, off, 64));
        if (ln == 0) wred[wv] = mx;
        __syncthreads();
        float s1mx = fmaxf(fmaxf(wred[0], wred[1]), fmaxf(wred[2], wred[3]));
        float s2n = s2[n];
        float rmx = lrelu(s2n + s1mx);
        float sum = 0.f;
#pragma unroll
        for (int j = 0; j < 16; ++j) if (mask & (1u << j)) sum += __expf(lrelu(s2n + sv[j]) - rmx);
        for (int off = 32; off > 0; off >>= 1) sum += __shfl_down(sum, off, 64);
        if (ln == 0) wred[4 + wv] = sum;
        __syncthreads();
        if (t == 0) {
            float tot = wred[4] + wred[5] + wred[6] + wred[7];
            bool any = s1mx > -2.9e38f;
            rowmax[n] = any ? rmx : 0.f;
            rowinv[n] = (any && tot > 0.f) ? 1.0f / tot : 0.f;
        }
    } else if (blockIdx.x < N_ + 2 * B_) {
        int bb = blockIdx.x - N_;
        int b = bb & (B_ - 1);
        bool isC = bb < B_;
        const int* adj = isC ? city : prov;
        uint32_t* BM = isC ? BMtc : BMtp;
        float* wout = isC ? w3 : w4;
        const int* rowp = adj + (size_t)src[b] * N_;
        int cnt = 0;
#pragma unroll 4
        for (int i = 0; i < N_ / 256; ++i) {
            int v = rowp[i * 256 + t];
            unsigned long long bal = __ballot(v > 0);
            cnt += (v > 0);
            if (ln == 0) {
                int widx = i * 8 + wv * 2;
                BM[(size_t)widx * B_ + b] = (uint32_t)bal;
                BM[(size_t)(widx + 1) * B_ + b] = (uint32_t)(bal >> 32);
            }
        }
        float fc = (float)cnt;
        for (int off = 32; off > 0; off >>= 1) fc += __shfl_down(fc, off, 64);
        if (ln == 0) wred[wv] = fc;
        __syncthreads();
        if (t == 0) {
            float tot = wred[0] + wred[1] + wred[2] + wred[3];
            wout[b] = tot > 0.f ? 1.0f / tot : 0.f;
        }
    } else {
        int bblk = blockIdx.x - (N_ + 2 * B_);            // 64 blocks
        int f = t & 127, halfb = t >> 7;
        vs8 o0, o1;
#pragma unroll
        for (int i = 0; i < 8; ++i) {
            int b0 = bblk * 32 + halfb * 16 + i;
            o0[i] = (short)f2b(h2[(size_t)src[b0] * F_ + f]);
            int b1 = b0 + 8;
            o1[i] = (short)f2b(h2[(size_t)src[b1] * F_ + f]);
        }
        unsigned short* dst = h2wP + ((size_t)bblk * 128 + f) * 32 + halfb * 16;
        *(vs8*)dst = o0;
        *(vs8*)(dst + 8) = o1;
    }
}

// ---- materialize att: packed attP[mblk][n][m&31] AND transposed attT[nblk][m][n&31] ----
// Lane remap vs R11: mo = t&7 (m-octet), nl = t>>3 (n) -> bm8 reads are 8 consecutive
// bytes per 8-lane group instead of a 512B-stride byte gather.
__global__ __launch_bounds__(256) void k_attmat2(const unsigned char* __restrict__ bm8,
                                                 const float* __restrict__ s1, const float* __restrict__ s2,
                                                 const float* __restrict__ rowmax, const float* __restrict__ rowinv,
                                                 unsigned short* __restrict__ attP,
                                                 unsigned short* __restrict__ attT) {
    __shared__ unsigned short tile[64][33];              // [m_local][n_local], padded
    int bx = blockIdx.x;                                 // 16384 = (M/64) x (N/32)
    int mt = bx & 63, nt = bx >> 6;
    int nb = nt * 32, mb = mt * 64;
    int t = threadIdx.x;
    int mo = t & 7, nl = t >> 3;                         // mo 0..7, nl 0..31
    int n = nb + nl;
    int m = mb + mo * 8;
    unsigned bits = bm8[(size_t)n * 512 + (m >> 3)];
    float s2n = s2[n], rmx = rowmax[n], rin = rowinv[n];
    float4 sa = *(const float4*)(s1 + m);
    float4 sb = *(const float4*)(s1 + m + 4);
    float sv[8] = {sa.x, sa.y, sa.z, sa.w, sb.x, sb.y, sb.z, sb.w};
    vs8 o;
#pragma unroll
    for (int j = 0; j < 8; ++j) {
        float v = (bits & (1u << j)) ? __expf(lrelu(s2n + sv[j]) - rmx) * rin : 0.f;
        o[j] = (short)f2b(v);
        tile[mo * 8 + j][nl] = (unsigned short)o[j];
    }
    *(vs8*)(attP + ((size_t)(m >> 5) * N_ + n) * 32 + (m & 31)) = o;
    __syncthreads();
    int mr = t >> 2, sg = t & 3;                         // mr 0..63, sg 0..3
    vs8 ot;
#pragma unroll
    for (int j = 0; j < 8; ++j) ot[j] = (short)tile[mr][sg * 8 + j];
    *(vs8*)(attT + ((size_t)nt * M_ + mb + mr) * 32 + sg * 8) = ot;
}

// ---- MERGED gemmA | gemmB | gemmC — dense partial-buffer outputs (NO atomics) ----
__global__ __launch_bounds__(256) void k_gemmABC(const unsigned short* __restrict__ attP,
                                                 const unsigned short* __restrict__ attT,
                                                 const unsigned short* __restrict__ h1P,
                                                 const unsigned short* __restrict__ h2P,
                                                 const uint32_t* __restrict__ BMtc, const uint32_t* __restrict__ BMtp,
                                                 const float* __restrict__ w3, const float* __restrict__ w4,
                                                 const unsigned short* __restrict__ h2wP,
                                                 float* __restrict__ uP, float* __restrict__ vP) {
    int t = threadIdx.x;
    int w = t >> 6, l = t & 63;
    int lr = l & 15, lg = l >> 4;
    int bx = blockIdx.x;
    if (bx < 1024) {
        // gemmA (bx<512): uP[y] = att @ h1 K-slice.  gemmB: vP[y] = att.T @ h2 K-slice.
        bool isA = bx < 512;
        int i = isA ? bx : bx - 512;
        int x, y, kbase;
        const unsigned short* Asrc; const unsigned short* Bsrc; float* Out;
        if (isA) { x = i & 127; y = i >> 7; kbase = y * 32;      // 128 x 4, K=128 mblks
                   Asrc = attP; Bsrc = h1P; Out = uP + (size_t)y * N_ * F_; }
        else     { x = i & 63;  y = i >> 6; kbase = y * 32;      // 64 x 8, K=256 nblks
                   Asrc = attT; Bsrc = h2P; Out = vP + (size_t)y * M_ * F_; }
        int rb0 = x * 64 + (w & 1) * 32;                 // output-row base
        int fb = (w >> 1) * 64;
        vf4 acc[2][4] = {};
        int rowsK = isA ? N_ : M_;
        size_t aoff = (size_t)(rb0 + lr) * 32 + lg * 8;
        const unsigned short* apm = Asrc + (size_t)kbase * rowsK * 32 + aoff;
        size_t astride = (size_t)rowsK * 32;
        ABu a0, a1;
        a0.s = *(const vs8*)apm;
        a1.s = *(const vs8*)(apm + 16 * 32);
        for (int it = 0; it < 32; ++it) {
            const unsigned short* hb = Bsrc + (size_t)(kbase + it) * 128 * 32;
            ABu b0, b1, b2, b3;
            b0.s = *(const vs8*)(hb + (size_t)(fb + lr) * 32 + lg * 8);
            b1.s = *(const vs8*)(hb + (size_t)(fb + 16 + lr) * 32 + lg * 8);
            b2.s = *(const vs8*)(hb + (size_t)(fb + 32 + lr) * 32 + lg * 8);
            b3.s = *(const vs8*)(hb + (size_t)(fb + 48 + lr) * 32 + lg * 8);
            const unsigned short* apn = apm + (it < 31 ? astride : 0);
            ABu a0n, a1n;
            a0n.s = *(const vs8*)apn;
            a1n.s = *(const vs8*)(apn + 16 * 32);
            acc[0][0] = mfma16(a0, b0, acc[0][0]);
            acc[1][0] = mfma16(a1, b0, acc[1][0]);
            acc[0][1] = mfma16(a0, b1, acc[0][1]);
            acc[1][1] = mfma16(a1, b1, acc[1][1]);
            acc[0][2] = mfma16(a0, b2, acc[0][2]);
            acc[1][2] = mfma16(a1, b2, acc[1][2]);
            acc[0][3] = mfma16(a0, b3, acc[0][3]);
            acc[1][3] = mfma16(a1, b3, acc[1][3]);
            a0 = a0n; a1 = a1n;
            apm = apn;
        }
#pragma unroll
        for (int s = 0; s < 2; ++s)
#pragma unroll
            for (int q = 0; q < 4; ++q)
#pragma unroll
                for (int r = 0; r < 4; ++r)
                    Out[(size_t)(rb0 + s * 16 + lg * 4 + r) * F_ + fb + q * 16 + lr] = acc[s][q][r];
    } else {
        // ---- gemmC: uP[4+y] = G @ h2w K-slice.  G on-the-fly from transposed bitmasks ----
        int i = bx - 1024;
        int xc = i & 127, yc = i >> 7;                   // 128 x 4
        int nb0 = xc * 64 + (w & 1) * 32;                // 32-aligned -> wi uniform per wave
        int fb = (w >> 1) * 64;
        int wi = nb0 >> 5;
        const uint32_t* bc = BMtc + (size_t)wi * B_;
        const uint32_t* bp = BMtp + (size_t)wi * B_;
        vf4 acc[2][4] = {};
        int b0s = yc * (B_ / 4);
        for (int b0 = b0s; b0 < b0s + B_ / 4; b0 += 32) {
            int bb = b0 + lg * 8;
            uint4 c0 = *(const uint4*)(bc + bb);
            uint4 c1 = *(const uint4*)(bc + bb + 4);
            uint4 p0 = *(const uint4*)(bp + bb);
            uint4 p1 = *(const uint4*)(bp + bb + 4);
            float4 wa = *(const float4*)(w3 + bb);
            float4 wb = *(const float4*)(w3 + bb + 4);
            float4 wc = *(const float4*)(w4 + bb);
            float4 wd = *(const float4*)(w4 + bb + 4);
            const unsigned short* hb = h2wP + (size_t)(b0 >> 5) * 128 * 32;
            ABu bf0, bf1, bf2, bf3;
            bf0.s = *(const vs8*)(hb + (size_t)(fb + lr) * 32 + lg * 8);
            bf1.s = *(const vs8*)(hb + (size_t)(fb + 16 + lr) * 32 + lg * 8);
            bf2.s = *(const vs8*)(hb + (size_t)(fb + 32 + lr) * 32 + lg * 8);
            bf3.s = *(const vs8*)(hb + (size_t)(fb + 48 + lr) * 32 + lg * 8);
            uint32_t cw[8] = {c0.x, c0.y, c0.z, c0.w, c1.x, c1.y, c1.z, c1.w};
            uint32_t pw[8] = {p0.x, p0.y, p0.z, p0.w, p1.x, p1.y, p1.z, p1.w};
            float w3v[8] = {wa.x, wa.y, wa.z, wa.w, wb.x, wb.y, wb.z, wb.w};
            float w4v[8] = {wc.x, wc.y, wc.z, wc.w, wd.x, wd.y, wd.z, wd.w};
            ABu af0, af1;
#pragma unroll
            for (int j = 0; j < 8; ++j) {
                float v0 = (((cw[j] >> lr) & 1u) ? w3v[j] : 0.f) + (((pw[j] >> lr) & 1u) ? w4v[j] : 0.f);
                float v1 = (((cw[j] >> (16 + lr)) & 1u) ? w3v[j] : 0.f) + (((pw[j] >> (16 + lr)) & 1u) ? w4v[j] : 0.f);
                af0.s[j] = (short)f2b(v0);
                af1.s[j] = (short)f2b(v1);
            }
            acc[0][0] = mfma16(af0, bf0, acc[0][0]);
            acc[1][0] = mfma16(af1, bf0, acc[1][0]);
            acc[0][1] = mfma16(af0, bf1, acc[0][1]);
            acc[1][1] = mfma16(af1, bf1, acc[1][1]);
            acc[0][2] = mfma16(af0, bf2, acc[0][2]);
            acc[1][2] = mfma16(af1, bf2, acc[1][2]);
            acc[0][3] = mfma16(af0, bf3, acc[0][3]);
            acc[1][3] = mfma16(af1, bf3, acc[1][3]);
        }
        float* Out = uP + (size_t)(4 + yc) * N_ * F_;
#pragma unroll
        for (int s = 0; s < 2; ++s)
#pragma unroll
            for (int q = 0; q < 4; ++q)
#pragma unroll
                for (int r = 0; r < 4; ++r)
                    Out[(size_t)(nb0 + s * 16 + lg * 4 + r) * F_ + fb + q * 16 + lr] = acc[s][q][r];
    }
}

// ---- sum 8 partials -> u_in/v_in + batchnorm column stats in one pass ----
__global__ __launch_bounds__(256) void k_bnreduce(const float* __restrict__ vP, const float* __restrict__ uP,
                                                  float* __restrict__ v_in, float* __restrict__ u_in,
                                                  float* __restrict__ stats) {
    __shared__ float r1[256], r2[256];
    int bx = blockIdx.x;
    const float* P; float* O; int R, nb_; size_t stride; float* sum; float* sq;
    if (bx < 256) { P = vP; O = v_in; R = M_; nb_ = 256; stride = (size_t)M_ * F_;
                    sum = stats; sq = stats + 128; }
    else          { P = uP; O = u_in; R = N_; nb_ = 512; stride = (size_t)N_ * F_;
                    sum = stats + 256; sq = stats + 384; bx -= 256; }
    int f = threadIdx.x & 127;
    int half = threadIdx.x >> 7;
    float s = 0.f, s2v = 0.f;
    for (int r = bx * 2 + half; r < R; r += nb_ * 2) {
        float v = 0.f;
#pragma unroll
        for (int y = 0; y < 8; ++y) v += P[(size_t)y * stride + (size_t)r * F_ + f];
        O[(size_t)r * F_ + f] = v;
        s += v; s2v += v * v;
    }
    r1[threadIdx.x] = s; r2[threadIdx.x] = s2v;
    __syncthreads();
    if (half == 0) {
        atomicAdd(&sum[f], r1[f] + r1[f + 128]);
        atomicAdd(&sq[f], r2[f] + r2[f + 128]);
    }
}

// ---- bn finalize (per-block recompute) + apply + leaky + cast bf16, float4-vectorized ----
__global__ __launch_bounds__(256) void k_bnapplyF(const float* __restrict__ v_in, const float* __restrict__ u_in,
                                                  const float* __restrict__ stats,
                                                  const float* __restrict__ g1, const float* __restrict__ b1,
                                                  const float* __restrict__ g2, const float* __restrict__ b2,
                                                  unsigned short* __restrict__ v_outb, unsigned short* __restrict__ u_outb) {
    __shared__ float sc[256], sh[256];                    // [which*128+f]
    int t = threadIdx.x;
    {
        int which = t >> 7, f = t & 127;
        const float* sum = stats + which * 256;
        const float* sq = sum + 128;
        const float* g = which ? g2 : g1;
        const float* be = which ? b2 : b1;
        float R = which ? (float)N_ : (float)M_;
        float mean = sum[f] / R;
        float var = sq[f] / R - mean * mean;
        float s = g[f] * rsqrtf(var + 1e-5f);
        sc[t] = s; sh[t] = be[f] - mean * s;
    }
    __syncthreads();
    int id4 = blockIdx.x * 256 + t;                       // one float4 per thread
    int idx = id4 * 4;
    int which = idx >= M_ * F_;
    int rel = which ? idx - M_ * F_ : idx;
    const float* P = which ? u_in : v_in;
    unsigned short* Q = which ? u_outb : v_outb;
    int f0 = (rel & 127) + which * 128;
    float4 p = *(const float4*)(P + rel);
    ushort4 o;
    o.x = f2b(lrelu(p.x * sc[f0 + 0] + sh[f0 + 0]));
    o.y = f2b(lrelu(p.y * sc[f0 + 1] + sh[f0 + 1]));
    o.z = f2b(lrelu(p.z * sc[f0 + 2] + sh[f0 + 2]));
    o.w = f2b(lrelu(p.w * sc[f0 + 3] + sh[f0 + 3]));
    *(ushort4*)(Q + rel) = o;
}

// ---------------- out = elu(U @ V^T) ----------------
__global__ __launch_bounds__(256) void k_gemmD(const unsigned short* __restrict__ U,
                                               const unsigned short* __restrict__ V,
                                               float* __restrict__ out) {
    int w = threadIdx.x >> 6, l = threadIdx.x & 63;
    int lr = l & 15, lg = l >> 4;
    int nb = blockIdx.x * 64 + w * 16;
    int mb = blockIdx.y * 64;
    vf4 acc[4] = {};
#pragma unroll
    for (int k0 = 0; k0 < F_; k0 += 32) {
        ABu af; af.s = *(const vs8*)(U + (size_t)(nb + lr) * F_ + k0 + lg * 8);
#pragma unroll
        for (int q = 0; q < 4; ++q) {
            ABu bf; bf.s = *(const vs8*)(V + (size_t)(mb + q * 16 + lr) * F_ + k0 + lg * 8);
            acc[q] = mfma16(af, bf, acc[q]);
        }
    }
#pragma unroll
    for (int q = 0; q < 4; ++q)
#pragma unroll
        for (int r = 0; r < 4; ++r) {
            int row = nb + lg * 4 + r;
            int col = mb + q * 16 + lr;
            float x = acc[q][r];
            out[(size_t)row * M_ + col] = x > 0.f ? x : __expf(x) - 1.f;
        }
}

extern "C" void kernel_launch(void* const* d_in, const int* in_sizes, int n_in,
                              void* d_out, int out_size, void* d_ws, size_t ws_size,
                              hipStream_t stream) {
    const float* Sinput = (const float*)d_in[0];
    const float* Rinput = (const float*)d_in[1];
    const int* inter_adj = (const int*)d_in[2];
    const int* city_adj = (const int*)d_in[3];
    const int* prov_adj = (const int*)d_in[4];
    const int* src = (const int*)d_in[5];
    const float* W1 = (const float*)d_in[6];
    const float* W2 = (const float*)d_in[7];
    const float* a = (const float*)d_in[8];
    const float* g1 = (const float*)d_in[11];
    const float* b1 = (const float*)d_in[12];
    const float* g2 = (const float*)d_in[13];
    const float* b2 = (const float*)d_in[14];
    float* out = (float*)d_out;

    char* ws = (char*)d_ws;
    size_t o = 0;
    auto take = [&](size_t bytes) { char* p = ws + o; o += (bytes + 255) & ~(size_t)255; return p; };
    float* stats = (float*)take(512 * 4);
    size_t zero_bytes = o;                               // ONLY stats zeroed now
    float* u_in = (float*)take((size_t)N_ * F_ * 4);
    float* v_in = (float*)take((size_t)M_ * F_ * 4);
    float* uP = (float*)take((size_t)8 * N_ * F_ * 4);   // 32 MB, gemmA y0..3 + gemmC y0..3
    float* vP = (float*)take((size_t)8 * M_ * F_ * 4);   // 16 MB, gemmB y0..7
    float* h2 = (float*)take((size_t)N_ * F_ * 4);
    unsigned short* h1P = (unsigned short*)take((size_t)(M_ / 32) * 128 * 32 * 2);
    unsigned short* h2P = (unsigned short*)take((size_t)(N_ / 32) * 128 * 32 * 2);
    unsigned short* W1T = (unsigned short*)take((size_t)F_ * FIN_ * 2);
    unsigned short* W2T = (unsigned short*)take((size_t)F_ * FIN_ * 2);
    float* s1 = (float*)take(M_ * 4);
    float* s2 = (float*)take(N_ * 4);
    float* rowmax = (float*)take(N_ * 4);
    float* rowinv = (float*)take(N_ * 4);
    float* w3 = (float*)take(B_ * 4);
    float* w4 = (float*)take(B_ * 4);
    unsigned short* h2wP = (unsigned short*)take((size_t)(B_ / 32) * 128 * 32 * 2);
    unsigned short* u_outb = (unsigned short*)take((size_t)N_ * F_ * 2);
    unsigned short* v_outb = (unsigned short*)take((size_t)M_ * F_ * 2);
    uint32_t* BMtc = (uint32_t*)take((size_t)256 * B_ * 4);
    uint32_t* BMtp = (uint32_t*)take((size_t)256 * B_ * 4);
    unsigned short* bm = (unsigned short*)take((size_t)N_ * 256 * 2);      // 4 MB, [n][m-bits]
    unsigned short* attP = (unsigned short*)take((size_t)N_ * M_ * 2);     // 64 MB packed
    unsigned short* attT = (unsigned short*)take((size_t)N_ * M_ * 2);     // 64 MB transposed-packed
    (void)ws_size; (void)in_sizes; (void)n_in; (void)out_size;

    int nz4 = (int)(zero_bytes / 16);
    int zblocks = (nz4 + 255) / 256;
    k_prep<<<256 + zblocks, 256, 0, stream>>>(W1, W2, W1T, W2T, (float4*)d_ws, nz4);
    k_hgemmF<<<(M_ + N_) / 16, 256, 0, stream>>>(Rinput, Sinput, W1T, W2T, a, h2, h1P, h2P, s1, s2);
    k_adjgather<<<N_ + 2 * B_ + B_ / 32, 256, 0, stream>>>(inter_adj, s1, s2, bm, rowmax, rowinv,
                                                           city_adj, prov_adj, src, BMtc, BMtp, w3, w4,
                                                           h2, h2wP);
    k_attmat2<<<16384, 256, 0, stream>>>((const unsigned char*)bm, s1, s2, rowmax, rowinv, attP, attT);
    k_gemmABC<<<1536, 256, 0, stream>>>(attP, attT, h1P, h2P, BMtc, BMtp, w3, w4, h2wP, uP, vP);
    k_bnreduce<<<768, 256, 0, stream>>>(vP, uP, v_in, u_in, stats);
    k_bnapplyF<<<(M_ + N_) * F_ / 4 / 256, 256, 0, stream>>>(v_in, u_in, stats, g1, b1, g2, b2, v_outb, u_outb);
    k_gemmD<<<dim3(N_ / 64, M_ / 64), 256, 0, stream>>>(u_outb, v_outb, out);
}

// Round 13
// 327.001 us; speedup vs baseline: 1.1920x; 1.0635x over previous
//
#include <hip/hip_runtime.h>
#include <stdint.h>

#define N_ 8192
#define M_ 4096
#define FIN_ 256
#define F_ 128
#define B_ 2048

typedef __attribute__((ext_vector_type(8))) short vs8;
typedef __attribute__((ext_vector_type(8))) __bf16 vb8;
typedef __attribute__((ext_vector_type(4))) float vf4;

union ABu { vs8 s; vb8 b; };

__device__ __forceinline__ vf4 mfma16(const ABu& a, const ABu& b, vf4 c) {
    return __builtin_amdgcn_mfma_f32_16x16x32_bf16(a.b, b.b, c, 0, 0, 0);
}
__device__ __forceinline__ unsigned short f2b(float x) {
    union { float f; unsigned u; } v; v.f = x;
    unsigned r = v.u + 0x7fffu + ((v.u >> 16) & 1u);
    return (unsigned short)(r >> 16);
}
__device__ __forceinline__ float lrelu(float x) { return x > 0.f ? x : 0.2f * x; }

// async global->LDS, 16B per lane; LDS dest = wave-uniform base + lane*16 (HW-added)
__device__ __forceinline__ void glds16(const unsigned short* g, void* l) {
    __builtin_amdgcn_global_load_lds((const __attribute__((address_space(1))) unsigned int*)g,
                                     (__attribute__((address_space(3))) unsigned int*)l, 16, 0, 0);
}

// ---- prep: W[256][128] f32 -> WT[128][256] bf16  +  zero stats (2KB only) ----
__global__ void k_prep(const float* __restrict__ W1, const float* __restrict__ W2,
                       unsigned short* __restrict__ W1T, unsigned short* __restrict__ W2T,
                       float4* __restrict__ Z, int nz4) {
    int id = blockIdx.x * 256 + threadIdx.x;
    if (id < 65536) {
        const float* W = (id < 32768) ? W1 : W2;
        unsigned short* WT = (id < 32768) ? W1T : W2T;
        int o = id & 32767;
        int f = o >> 8, k = o & 255;
        WT[o] = f2b(W[k * F_ + f]);
    } else {
        int z = id - 65536;
        if (z < nz4) Z[z] = make_float4(0.f, 0.f, 0.f, 0.f);
    }
}

// ---- FUSED: h = X@W (MFMA); write h2 f32, packed hP[kblk][f][32] bf16, s1/s2 row-dots ----
__global__ __launch_bounds__(256) void k_hgemmF(const float* __restrict__ Rin, const float* __restrict__ Sin,
                                                const unsigned short* __restrict__ W1T,
                                                const unsigned short* __restrict__ W2T,
                                                const float* __restrict__ a,
                                                float* __restrict__ h2,
                                                unsigned short* __restrict__ h1P, unsigned short* __restrict__ h2P,
                                                float* __restrict__ s1, float* __restrict__ s2) {
    __shared__ unsigned short tb[16][136];               // 16 rows x 128 f, padded
    __shared__ float sred[4][16];
    int t = threadIdx.x;
    int w = t >> 6, l = t & 63, lr = l & 15, lg = l >> 4;
    int gr = blockIdx.x * 16;
    const float* X; const unsigned short* WT; unsigned short* HP; float* sout; const float* av;
    int row0; bool isH2;
    if (gr < M_) { X = Rin; WT = W1T; HP = h1P; sout = s1; av = a;      row0 = gr;      isH2 = false; }
    else         { X = Sin; WT = W2T; HP = h2P; sout = s2; av = a + F_; row0 = gr - M_; isH2 = true;  }
    int fbase = w * 32;
    vf4 acc[2] = {};
    const float* xp = X + (size_t)(row0 + lr) * FIN_ + lg * 8;
#pragma unroll
    for (int kk = 0; kk < FIN_; kk += 32) {
        float4 xa = *(const float4*)(xp + kk);
        float4 xb = *(const float4*)(xp + kk + 4);
        ABu af;
        af.s[0] = (short)f2b(xa.x); af.s[1] = (short)f2b(xa.y);
        af.s[2] = (short)f2b(xa.z); af.s[3] = (short)f2b(xa.w);
        af.s[4] = (short)f2b(xb.x); af.s[5] = (short)f2b(xb.y);
        af.s[6] = (short)f2b(xb.z); af.s[7] = (short)f2b(xb.w);
#pragma unroll
        for (int q = 0; q < 2; ++q) {
            ABu bf; bf.s = *(const vs8*)(WT + (fbase + q * 16 + lr) * FIN_ + kk + lg * 8);
            acc[q] = mfma16(af, bf, acc[q]);
        }
    }
    if (isH2) {
#pragma unroll
        for (int q = 0; q < 2; ++q)
#pragma unroll
            for (int r = 0; r < 4; ++r)
                h2[(size_t)(row0 + lg * 4 + r) * F_ + fbase + q * 16 + lr] = acc[q][r];
    }
#pragma unroll
    for (int q = 0; q < 2; ++q)
#pragma unroll
        for (int r = 0; r < 4; ++r)
            tb[lg * 4 + r][fbase + q * 16 + lr] = f2b(acc[q][r]);
    float a0 = av[fbase + lr], a1 = av[fbase + 16 + lr];
    float tv[4];
#pragma unroll
    for (int r = 0; r < 4; ++r) tv[r] = acc[0][r] * a0 + acc[1][r] * a1;
#pragma unroll
    for (int off = 1; off < 16; off <<= 1)
#pragma unroll
        for (int r = 0; r < 4; ++r) tv[r] += __shfl_xor(tv[r], off, 64);
    if ((l & 15) == 0)
#pragma unroll
        for (int r = 0; r < 4; ++r) sred[w][lg * 4 + r] = tv[r];
    __syncthreads();
    {
        int f = t >> 1, half = t & 1;
        vs8 o;
#pragma unroll
        for (int j = 0; j < 8; ++j) o[j] = (short)tb[half * 8 + j][f];
        *(vs8*)(HP + ((size_t)(row0 >> 5) * 128 + f) * 32 + (row0 & 16) + half * 8) = o;
    }
    if (t < 16) {
        float s = sred[0][t] + sred[1][t] + sred[2][t] + sred[3][t];
        sout[row0 + t] = s;
    }
}

// ---- FUSED: inter stats+bitmask | city/prov bitmask+counts | h2wP gather ----
__global__ __launch_bounds__(256) void k_adjgather(const int* __restrict__ inter, const float* __restrict__ s1,
                                                   const float* __restrict__ s2, unsigned short* __restrict__ bm,
                                                   float* __restrict__ rowmax, float* __restrict__ rowinv,
                                                   const int* __restrict__ city, const int* __restrict__ prov,
                                                   const int* __restrict__ src,
                                                   uint32_t* __restrict__ BMtc, uint32_t* __restrict__ BMtp,
                                                   float* __restrict__ w3, float* __restrict__ w4,
                                                   const float* __restrict__ h2, unsigned short* __restrict__ h2wP) {
    __shared__ float wred[8];
    int t = threadIdx.x;
    int wv = t >> 6, ln = t & 63;
    if (blockIdx.x < N_) {
        int n = blockIdx.x;
        const int* rp = inter + (size_t)n * M_ + t * 16;
        float sv[16]; unsigned mask = 0;
#pragma unroll
        for (int c = 0; c < 4; ++c) {
            int4 v = *(const int4*)(rp + c * 4);
            if (v.x > 0) mask |= 1u << (c * 4 + 0);
            if (v.y > 0) mask |= 1u << (c * 4 + 1);
            if (v.z > 0) mask |= 1u << (c * 4 + 2);
            if (v.w > 0) mask |= 1u << (c * 4 + 3);
            float4 s = *(const float4*)(s1 + t * 16 + c * 4);
            sv[c * 4 + 0] = s.x; sv[c * 4 + 1] = s.y; sv[c * 4 + 2] = s.z; sv[c * 4 + 3] = s.w;
        }
        bm[(size_t)n * 256 + t] = (unsigned short)(mask & 0xffffu);
        float mx = -3.0e38f;
#pragma unroll
        for (int j = 0; j < 16; ++j) if (mask & (1u << j)) mx = fmaxf(mx, sv[j]);
        for (int off = 32; off > 0; off >>= 1) mx = fmaxf(mx, __shfl_down(mx, off, 64));
        if (ln == 0) wred[wv] = mx;
        __syncthreads();
        float s1mx = fmaxf(fmaxf(wred[0], wred[1]), fmaxf(wred[2], wred[3]));
        float s2n = s2[n];
        float rmx = lrelu(s2n + s1mx);
        float sum = 0.f;
#pragma unroll
        for (int j = 0; j < 16; ++j) if (mask & (1u << j)) sum += __expf(lrelu(s2n + sv[j]) - rmx);
        for (int off = 32; off > 0; off >>= 1) sum += __shfl_down(sum, off, 64);
        if (ln == 0) wred[4 + wv] = sum;
        __syncthreads();
        if (t == 0) {
            float tot = wred[4] + wred[5] + wred[6] + wred[7];
            bool any = s1mx > -2.9e38f;
            rowmax[n] = any ? rmx : 0.f;
            rowinv[n] = (any && tot > 0.f) ? 1.0f / tot : 0.f;
        }
    } else if (blockIdx.x < N_ + 2 * B_) {
        int bb = blockIdx.x - N_;
        int b = bb & (B_ - 1);
        bool isC = bb < B_;
        const int* adj = isC ? city : prov;
        uint32_t* BM = isC ? BMtc : BMtp;
        float* wout = isC ? w3 : w4;
        const int* rowp = adj + (size_t)src[b] * N_;
        int cnt = 0;
#pragma unroll 4
        for (int i = 0; i < N_ / 256; ++i) {
            int v = rowp[i * 256 + t];
            unsigned long long bal = __ballot(v > 0);
            cnt += (v > 0);
            if (ln == 0) {
                int widx = i * 8 + wv * 2;
                BM[(size_t)widx * B_ + b] = (uint32_t)bal;
                BM[(size_t)(widx + 1) * B_ + b] = (uint32_t)(bal >> 32);
            }
        }
        float fc = (float)cnt;
        for (int off = 32; off > 0; off >>= 1) fc += __shfl_down(fc, off, 64);
        if (ln == 0) wred[wv] = fc;
        __syncthreads();
        if (t == 0) {
            float tot = wred[0] + wred[1] + wred[2] + wred[3];
            wout[b] = tot > 0.f ? 1.0f / tot : 0.f;
        }
    } else {
        int bblk = blockIdx.x - (N_ + 2 * B_);            // 64 blocks
        int f = t & 127, halfb = t >> 7;
        vs8 o0, o1;
#pragma unroll
        for (int i = 0; i < 8; ++i) {
            int b0 = bblk * 32 + halfb * 16 + i;
            o0[i] = (short)f2b(h2[(size_t)src[b0] * F_ + f]);
            int b1 = b0 + 8;
            o1[i] = (short)f2b(h2[(size_t)src[b1] * F_ + f]);
        }
        unsigned short* dst = h2wP + ((size_t)bblk * 128 + f) * 32 + halfb * 16;
        *(vs8*)dst = o0;
        *(vs8*)(dst + 8) = o1;
    }
}

// ---- materialize att: packed attP[mblk][n][m&31] AND transposed attT[nblk][m][n&31] ----
__global__ __launch_bounds__(256) void k_attmat2(const unsigned char* __restrict__ bm8,
                                                 const float* __restrict__ s1, const float* __restrict__ s2,
                                                 const float* __restrict__ rowmax, const float* __restrict__ rowinv,
                                                 unsigned short* __restrict__ attP,
                                                 unsigned short* __restrict__ attT) {
    __shared__ unsigned short tile[64][33];              // [m_local][n_local], padded
    int bx = blockIdx.x;                                 // 16384 = (M/64) x (N/32)
    int mt = bx & 63, nt = bx >> 6;
    int nb = nt * 32, mb = mt * 64;
    int t = threadIdx.x;
    int mo = t & 7, nl = t >> 3;                         // mo 0..7, nl 0..31
    int n = nb + nl;
    int m = mb + mo * 8;
    unsigned bits = bm8[(size_t)n * 512 + (m >> 3)];
    float s2n = s2[n], rmx = rowmax[n], rin = rowinv[n];
    float4 sa = *(const float4*)(s1 + m);
    float4 sb = *(const float4*)(s1 + m + 4);
    float sv[8] = {sa.x, sa.y, sa.z, sa.w, sb.x, sb.y, sb.z, sb.w};
    vs8 o;
#pragma unroll
    for (int j = 0; j < 8; ++j) {
        float v = (bits & (1u << j)) ? __expf(lrelu(s2n + sv[j]) - rmx) * rin : 0.f;
        o[j] = (short)f2b(v);
        tile[mo * 8 + j][nl] = (unsigned short)o[j];
    }
    *(vs8*)(attP + ((size_t)(m >> 5) * N_ + n) * 32 + (m & 31)) = o;
    __syncthreads();
    int mr = t >> 2, sg = t & 3;                         // mr 0..63, sg 0..3
    vs8 ot;
#pragma unroll
    for (int j = 0; j < 8; ++j) ot[j] = (short)tile[mr][sg * 8 + j];
    *(vs8*)(attT + ((size_t)nt * M_ + mb + mr) * 32 + sg * 8) = ot;
}

// ---- MERGED gemmA | gemmB (2-phase LDS pipeline via global_load_lds) | gemmC ----
__global__ __launch_bounds__(256) void k_gemmABC(const unsigned short* __restrict__ attP,
                                                 const unsigned short* __restrict__ attT,
                                                 const unsigned short* __restrict__ h1P,
                                                 const unsigned short* __restrict__ h2P,
                                                 const uint32_t* __restrict__ BMtc, const uint32_t* __restrict__ BMtp,
                                                 const float* __restrict__ w3, const float* __restrict__ w4,
                                                 const unsigned short* __restrict__ h2wP,
                                                 float* __restrict__ uP, float* __restrict__ vP) {
    __shared__ __align__(16) unsigned short smem[24576];  // 48 KB: 2 x (A 8KB + B 16KB)
    int t = threadIdx.x;
    int w = t >> 6, l = t & 63;
    int lr = l & 15, lg = l >> 4;
    int bx = blockIdx.x;
    if (bx < 1024) {
        // gemmA (bx<512): uP[y] = att @ h1 K-slice.  gemmB: vP[y] = att.T @ h2 K-slice.
        bool isA = bx < 512;
        int i = isA ? bx : bx - 512;
        int x, y, rowsK;
        const unsigned short* Asrc; const unsigned short* Bsrc; float* Out;
        if (isA) { x = i & 127; y = i >> 7; Asrc = attP; Bsrc = h1P;
                   Out = uP + (size_t)y * N_ * F_; rowsK = N_; }
        else     { x = i & 63;  y = i >> 6; Asrc = attT; Bsrc = h2P;
                   Out = vP + (size_t)y * M_ * F_; rowsK = M_; }
        int kbase = y * 32;                              // in 32-k blocks; 16 steps x 2 blocks
        int rb0b = x * 64;                               // block row base
        int rh = (w & 1) * 32;                           // wave row-half
        int fb = (w >> 1) * 64;                          // wave f-half
        int ch0 = w * 6;                                 // this wave's 6 staging chunks (of 24)
        auto stage = [&](int step, int curb) {
#pragma unroll
            for (int ii = 0; ii < 6; ++ii) {
                int c = ch0 + ii;
                const unsigned short* g; int loff;
                if (c < 8) {                             // A: 2 kb x 4KB (64 rows x 64B)
                    int kb = c >> 2;
                    g = Asrc + (size_t)(kbase + 2 * step + kb) * rowsK * 32 + rb0b * 32
                        + (c & 3) * 512 + l * 8;
                    loff = curb * 24576 + kb * 4096 + (c & 3) * 1024;
                } else {                                 // B: 2 kb x 8KB (128 f x 64B)
                    int c2 = c - 8;
                    int kb = c2 >> 3;
                    g = Bsrc + (size_t)(kbase + 2 * step + kb) * 4096 + (c2 & 7) * 512 + l * 8;
                    loff = curb * 24576 + 8192 + kb * 8192 + (c2 & 7) * 1024;
                }
                glds16(g, (char*)smem + loff);
            }
        };
        vf4 acc[2][4] = {};
        stage(0, 0);
        __syncthreads();
        int cur = 0;
        for (int step = 0; step < 16; ++step) {
            if (step < 15) stage(step + 1, cur ^ 1);
            const char* base = (const char*)smem + cur * 24576;
#pragma unroll
            for (int kb = 0; kb < 2; ++kb) {
                ABu a0, a1, b0, b1, b2, b3;
                a0.s = *(const vs8*)(base + kb * 4096 + (rh + lr) * 64 + lg * 16);
                a1.s = *(const vs8*)(base + kb * 4096 + (rh + 16 + lr) * 64 + lg * 16);
                b0.s = *(const vs8*)(base + 8192 + kb * 8192 + (fb + lr) * 64 + lg * 16);
                b1.s = *(const vs8*)(base + 8192 + kb * 8192 + (fb + 16 + lr) * 64 + lg * 16);
                b2.s = *(const vs8*)(base + 8192 + kb * 8192 + (fb + 32 + lr) * 64 + lg * 16);
                b3.s = *(const vs8*)(base + 8192 + kb * 8192 + (fb + 48 + lr) * 64 + lg * 16);
                acc[0][0] = mfma16(a0, b0, acc[0][0]);
                acc[1][0] = mfma16(a1, b0, acc[1][0]);
                acc[0][1] = mfma16(a0, b1, acc[0][1]);
                acc[1][1] = mfma16(a1, b1, acc[1][1]);
                acc[0][2] = mfma16(a0, b2, acc[0][2]);
                acc[1][2] = mfma16(a1, b2, acc[1][2]);
                acc[0][3] = mfma16(a0, b3, acc[0][3]);
                acc[1][3] = mfma16(a1, b3, acc[1][3]);
            }
            __syncthreads();                             // drains stage vmcnt + ds reads
            cur ^= 1;
        }
#pragma unroll
        for (int s = 0; s < 2; ++s)
#pragma unroll
            for (int q = 0; q < 4; ++q)
#pragma unroll
                for (int r = 0; r < 4; ++r)
                    Out[(size_t)(rb0b + rh + s * 16 + lg * 4 + r) * F_ + fb + q * 16 + lr] = acc[s][q][r];
    } else {
        // ---- gemmC: uP[4+y] = G @ h2w K-slice.  G on-the-fly from transposed bitmasks ----
        int i = bx - 1024;
        int xc = i & 127, yc = i >> 7;                   // 128 x 4
        int nb0 = xc * 64 + (w & 1) * 32;                // 32-aligned -> wi uniform per wave
        int fb = (w >> 1) * 64;
        int wi = nb0 >> 5;
        const uint32_t* bc = BMtc + (size_t)wi * B_;
        const uint32_t* bp = BMtp + (size_t)wi * B_;
        vf4 acc[2][4] = {};
        int b0s = yc * (B_ / 4);
        for (int b0 = b0s; b0 < b0s + B_ / 4; b0 += 32) {
            int bb = b0 + lg * 8;
            uint4 c0 = *(const uint4*)(bc + bb);
            uint4 c1 = *(const uint4*)(bc + bb + 4);
            uint4 p0 = *(const uint4*)(bp + bb);
            uint4 p1 = *(const uint4*)(bp + bb + 4);
            float4 wa = *(const float4*)(w3 + bb);
            float4 wb = *(const float4*)(w3 + bb + 4);
            float4 wc = *(const float4*)(w4 + bb);
            float4 wd = *(const float4*)(w4 + bb + 4);
            const unsigned short* hb = h2wP + (size_t)(b0 >> 5) * 128 * 32;
            ABu bf0, bf1, bf2, bf3;
            bf0.s = *(const vs8*)(hb + (size_t)(fb + lr) * 32 + lg * 8);
            bf1.s = *(const vs8*)(hb + (size_t)(fb + 16 + lr) * 32 + lg * 8);
            bf2.s = *(const vs8*)(hb + (size_t)(fb + 32 + lr) * 32 + lg * 8);
            bf3.s = *(const vs8*)(hb + (size_t)(fb + 48 + lr) * 32 + lg * 8);
            uint32_t cw[8] = {c0.x, c0.y, c0.z, c0.w, c1.x, c1.y, c1.z, c1.w};
            uint32_t pw[8] = {p0.x, p0.y, p0.z, p0.w, p1.x, p1.y, p1.z, p1.w};
            float w3v[8] = {wa.x, wa.y, wa.z, wa.w, wb.x, wb.y, wb.z, wb.w};
            float w4v[8] = {wc.x, wc.y, wc.z, wc.w, wd.x, wd.y, wd.z, wd.w};
            ABu af0, af1;
#pragma unroll
            for (int j = 0; j < 8; ++j) {
                float v0 = (((cw[j] >> lr) & 1u) ? w3v[j] : 0.f) + (((pw[j] >> lr) & 1u) ? w4v[j] : 0.f);
                float v1 = (((cw[j] >> (16 + lr)) & 1u) ? w3v[j] : 0.f) + (((pw[j] >> (16 + lr)) & 1u) ? w4v[j] : 0.f);
                af0.s[j] = (short)f2b(v0);
                af1.s[j] = (short)f2b(v1);
            }
            acc[0][0] = mfma16(af0, bf0, acc[0][0]);
            acc[1][0] = mfma16(af1, bf0, acc[1][0]);
            acc[0][1] = mfma16(af0, bf1, acc[0][1]);
            acc[1][1] = mfma16(af1, bf1, acc[1][1]);
            acc[0][2] = mfma16(af0, bf2, acc[0][2]);
            acc[1][2] = mfma16(af1, bf2, acc[1][2]);
            acc[0][3] = mfma16(af0, bf3, acc[0][3]);
            acc[1][3] = mfma16(af1, bf3, acc[1][3]);
        }
        float* Out = uP + (size_t)(4 + yc) * N_ * F_;
#pragma unroll
        for (int s = 0; s < 2; ++s)
#pragma unroll
            for (int q = 0; q < 4; ++q)
#pragma unroll
                for (int r = 0; r < 4; ++r)
                    Out[(size_t)(nb0 + s * 16 + lg * 4 + r) * F_ + fb + q * 16 + lr] = acc[s][q][r];
    }
}

// ---- sum 8 partials -> u_in/v_in + batchnorm column stats in one pass ----
__global__ __launch_bounds__(256) void k_bnreduce(const float* __restrict__ vP, const float* __restrict__ uP,
                                                  float* __restrict__ v_in, float* __restrict__ u_in,
                                                  float* __restrict__ stats) {
    __shared__ float r1[256], r2[256];
    int bx = blockIdx.x;
    const float* P; float* O; int R, nb_; size_t stride; float* sum; float* sq;
    if (bx < 256) { P = vP; O = v_in; R = M_; nb_ = 256; stride = (size_t)M_ * F_;
                    sum = stats; sq = stats + 128; }
    else          { P = uP; O = u_in; R = N_; nb_ = 512; stride = (size_t)N_ * F_;
                    sum = stats + 256; sq = stats + 384; bx -= 256; }
    int f = threadIdx.x & 127;
    int half = threadIdx.x >> 7;
    float s = 0.f, s2v = 0.f;
    for (int r = bx * 2 + half; r < R; r += nb_ * 2) {
        float v = 0.f;
#pragma unroll
        for (int y = 0; y < 8; ++y) v += P[(size_t)y * stride + (size_t)r * F_ + f];
        O[(size_t)r * F_ + f] = v;
        s += v; s2v += v * v;
    }
    r1[threadIdx.x] = s; r2[threadIdx.x] = s2v;
    __syncthreads();
    if (half == 0) {
        atomicAdd(&sum[f], r1[f] + r1[f + 128]);
        atomicAdd(&sq[f], r2[f] + r2[f + 128]);
    }
}

// ---- bn finalize (per-block recompute) + apply + leaky + cast bf16, float4-vectorized ----
__global__ __launch_bounds__(256) void k_bnapplyF(const float* __restrict__ v_in, const float* __restrict__ u_in,
                                                  const float* __restrict__ stats,
                                                  const float* __restrict__ g1, const float* __restrict__ b1,
                                                  const float* __restrict__ g2, const float* __restrict__ b2,
                                                  unsigned short* __restrict__ v_outb, unsigned short* __restrict__ u_outb) {
    __shared__ float sc[256], sh[256];                    // [which*128+f]
    int t = threadIdx.x;
    {
        int which = t >> 7, f = t & 127;
        const float* sum = stats + which * 256;
        const float* sq = sum + 128;
        const float* g = which ? g2 : g1;
        const float* be = which ? b2 : b1;
        float R = which ? (float)N_ : (float)M_;
        float mean = sum[f] / R;
        float var = sq[f] / R - mean * mean;
        float s = g[f] * rsqrtf(var + 1e-5f);
        sc[t] = s; sh[t] = be[f] - mean * s;
    }
    __syncthreads();
    int id4 = blockIdx.x * 256 + t;                       // one float4 per thread
    int idx = id4 * 4;
    int which = idx >= M_ * F_;
    int rel = which ? idx - M_ * F_ : idx;
    const float* P = which ? u_in : v_in;
    unsigned short* Q = which ? u_outb : v_outb;
    int f0 = (rel & 127) + which * 128;
    float4 p = *(const float4*)(P + rel);
    ushort4 o;
    o.x = f2b(lrelu(p.x * sc[f0 + 0] + sh[f0 + 0]));
    o.y = f2b(lrelu(p.y * sc[f0 + 1] + sh[f0 + 1]));
    o.z = f2b(lrelu(p.z * sc[f0 + 2] + sh[f0 + 2]));
    o.w = f2b(lrelu(p.w * sc[f0 + 3] + sh[f0 + 3]));
    *(ushort4*)(Q + rel) = o;
}

// ---------------- out = elu(U @ V^T) ----------------
__global__ __launch_bounds__(256) void k_gemmD(const unsigned short* __restrict__ U,
                                               const unsigned short* __restrict__ V,
                                               float* __restrict__ out) {
    int w = threadIdx.x >> 6, l = threadIdx.x & 63;
    int lr = l & 15, lg = l >> 4;
    int nb = blockIdx.x * 64 + w * 16;
    int mb = blockIdx.y * 64;
    vf4 acc[4] = {};
#pragma unroll
    for (int k0 = 0; k0 < F_; k0 += 32) {
        ABu af; af.s = *(const vs8*)(U + (size_t)(nb + lr) * F_ + k0 + lg * 8);
#pragma unroll
        for (int q = 0; q < 4; ++q) {
            ABu bf; bf.s = *(const vs8*)(V + (size_t)(mb + q * 16 + lr) * F_ + k0 + lg * 8);
            acc[q] = mfma16(af, bf, acc[q]);
        }
    }
#pragma unroll
    for (int q = 0; q < 4; ++q)
#pragma unroll
        for (int r = 0; r < 4; ++r) {
            int row = nb + lg * 4 + r;
            int col = mb + q * 16 + lr;
            float x = acc[q][r];
            out[(size_t)row * M_ + col] = x > 0.f ? x : __expf(x) - 1.f;
        }
}

extern "C" void kernel_launch(void* const* d_in, const int* in_sizes, int n_in,
                              void* d_out, int out_size, void* d_ws, size_t ws_size,
                              hipStream_t stream) {
    const float* Sinput = (const float*)d_in[0];
    const float* Rinput = (const float*)d_in[1];
    const int* inter_adj = (const int*)d_in[2];
    const int* city_adj = (const int*)d_in[3];
    const int* prov_adj = (const int*)d_in[4];
    const int* src = (const int*)d_in[5];
    const float* W1 = (const float*)d_in[6];
    const float* W2 = (const float*)d_in[7];
    const float* a = (const float*)d_in[8];
    const float* g1 = (const float*)d_in[11];
    const float* b1 = (const float*)d_in[12];
    const float* g2 = (const float*)d_in[13];
    const float* b2 = (const float*)d_in[14];
    float* out = (float*)d_out;

    char* ws = (char*)d_ws;
    size_t o = 0;
    auto take = [&](size_t bytes) { char* p = ws + o; o += (bytes + 255) & ~(size_t)255; return p; };
    float* stats = (float*)take(512 * 4);
    size_t zero_bytes = o;                               // ONLY stats zeroed
    float* u_in = (float*)take((size_t)N_ * F_ * 4);
    float* v_in = (float*)take((size_t)M_ * F_ * 4);
    float* uP = (float*)take((size_t)8 * N_ * F_ * 4);   // 32 MB, gemmA y0..3 + gemmC y0..3
    float* vP = (float*)take((size_t)8 * M_ * F_ * 4);   // 16 MB, gemmB y0..7
    float* h2 = (float*)take((size_t)N_ * F_ * 4);
    unsigned short* h1P = (unsigned short*)take((size_t)(M_ / 32) * 128 * 32 * 2);
    unsigned short* h2P = (unsigned short*)take((size_t)(N_ / 32) * 128 * 32 * 2);
    unsigned short* W1T = (unsigned short*)take((size_t)F_ * FIN_ * 2);
    unsigned short* W2T = (unsigned short*)take((size_t)F_ * FIN_ * 2);
    float* s1 = (float*)take(M_ * 4);
    float* s2 = (float*)take(N_ * 4);
    float* rowmax = (float*)take(N_ * 4);
    float* rowinv = (float*)take(N_ * 4);
    float* w3 = (float*)take(B_ * 4);
    float* w4 = (float*)take(B_ * 4);
    unsigned short* h2wP = (unsigned short*)take((size_t)(B_ / 32) * 128 * 32 * 2);
    unsigned short* u_outb = (unsigned short*)take((size_t)N_ * F_ * 2);
    unsigned short* v_outb = (unsigned short*)take((size_t)M_ * F_ * 2);
    uint32_t* BMtc = (uint32_t*)take((size_t)256 * B_ * 4);
    uint32_t* BMtp = (uint32_t*)take((size_t)256 * B_ * 4);
    unsigned short* bm = (unsigned short*)take((size_t)N_ * 256 * 2);      // 4 MB, [n][m-bits]
    unsigned short* attP = (unsigned short*)take((size_t)N_ * M_ * 2);     // 64 MB packed
    unsigned short* attT = (unsigned short*)take((size_t)N_ * M_ * 2);     // 64 MB transposed-packed
    (void)ws_size; (void)in_sizes; (void)n_in; (void)out_size;

    int nz4 = (int)(zero_bytes / 16);
    int zblocks = (nz4 + 255) / 256;
    k_prep<<<256 + zblocks, 256, 0, stream>>>(W1, W2, W1T, W2T, (float4*)d_ws, nz4);
    k_hgemmF<<<(M_ + N_) / 16, 256, 0, stream>>>(Rinput, Sinput, W1T, W2T, a, h2, h1P, h2P, s1, s2);
    k_adjgather<<<N_ + 2 * B_ + B_ / 32, 256, 0, stream>>>(inter_adj, s1, s2, bm, rowmax, rowinv,
                                                           city_adj, prov_adj, src, BMtc, BMtp, w3, w4,
                                                           h2, h2wP);
    k_attmat2<<<16384, 256, 0, stream>>>((const unsigned char*)bm, s1, s2, rowmax, rowinv, attP, attT);
    k_gemmABC<<<1536, 256, 0, stream>>>(attP, attT, h1P, h2P, BMtc, BMtp, w3, w4, h2wP, uP, vP);
    k_bnreduce<<<768, 256, 0, stream>>>(vP, uP, v_in, u_in, stats);
    k_bnapplyF<<<(M_ + N_) * F_ / 4 / 256, 256, 0, stream>>>(v_in, u_in, stats, g1, b1, g2, b2, v_outb, u_outb);
    k_gemmD<<<dim3(N_ / 64, M_ / 64), 256, 0, stream>>>(u_outb, v_outb, out);
}